// Round 4
// baseline (587.638 us; speedup 1.0000x reference)
//
#include <hip/hip_runtime.h>
#include <hip/hip_bf16.h>

typedef float f32x4 __attribute__((ext_vector_type(4)));
typedef float f32x16 __attribute__((ext_vector_type(16)));
typedef short s16x8 __attribute__((ext_vector_type(8)));
typedef uint  u32x4 __attribute__((ext_vector_type(4)));

#define MFMA_BF16(a, b, c) __builtin_amdgcn_mfma_f32_16x16x32_bf16((a), (b), (c), 0, 0, 0)
#define MFMA32(a, b, c)    __builtin_amdgcn_mfma_f32_32x32x16_bf16((a), (b), (c), 0, 0, 0)

// ---------- helpers ----------
__device__ __forceinline__ ushort f2bf(float f) {
  uint u = __builtin_bit_cast(uint, f);
  u += 0x7FFFu + ((u >> 16) & 1u);
  return (ushort)(u >> 16);
}
__device__ __forceinline__ uint pack2bf(float a, float b) {
  return (uint)f2bf(a) | ((uint)f2bf(b) << 16);
}
// exp(s - 30) written identically in stats and attn kernels
__device__ __forceinline__ float pexp(float s) {
  return exp2f(fmaf(s, 1.4426950408889634f, -43.2808512266689f));
}
__device__ __forceinline__ uint cvtpk(float lo, float hi) {
  uint r;
  asm("v_cvt_pk_bf16_f32 %0, %1, %2" : "=v"(r) : "v"(lo), "v"(hi));
  return r;
}
__device__ __forceinline__ void plswap(uint& a, uint& b) {
  asm("v_permlane32_swap_b32 %0, %1" : "+v"(a), "+v"(b));
}

// ---------- ws layout (bytes) ----------
#define WS_XT    0UL
#define WS_D     16777216UL
#define WS_BT    33554432UL
#define WS_CT    35651584UL
#define WS_WCAT  37748736UL
#define WS_BCAT  38404096UL

// ---------- kernel 1: pack weights to bf16 [640][512] + bias concat ----------
__global__ void k_prep_w(const float* __restrict__ Wb, const float* __restrict__ bb,
                         const float* __restrict__ Wc, const float* __restrict__ bc,
                         const float* __restrict__ Wd, const float* __restrict__ bd,
                         ushort* __restrict__ Wcat, float* __restrict__ bcat) {
  int idx = blockIdx.x * 256 + threadIdx.x;
  if (idx < 640 * 512) {
    int m = idx >> 9, k = idx & 511;
    float v = (m < 64) ? Wb[m * 512 + k] : (m < 128) ? Wc[(m - 64) * 512 + k] : Wd[(m - 128) * 512 + k];
    Wcat[idx] = f2bf(v);
  }
  if (idx < 640) {
    bcat[idx] = (idx < 64) ? bb[idx] : (idx < 128) ? bc[idx - 64] : bd[idx - 128];
  }
}

// ---------- kernel 2: transpose x [B][512][4096] f32 -> xT [B][4096][512] bf16 ----------
__global__ __launch_bounds__(256) void k_prep_xt(const float* __restrict__ x, ushort* __restrict__ xT) {
  __shared__ float tile[64][65];
  int bx = blockIdx.x;
  int b = bx >> 9;                  // 8*64 = 512 tiles per batch
  int c0 = ((bx >> 6) & 7) * 64;
  int n0 = (bx & 63) * 64;
  int t = threadIdx.x;
  const float* xb = x + (size_t)b * 512 * 4096;
#pragma unroll
  for (int p = 0; p < 4; ++p) {
    int cl = (t >> 4) + 16 * p;
    int nf = (t & 15) * 4;
    float4 v = *reinterpret_cast<const float4*>(xb + (size_t)(c0 + cl) * 4096 + n0 + nf);
    tile[cl][nf + 0] = v.x; tile[cl][nf + 1] = v.y; tile[cl][nf + 2] = v.z; tile[cl][nf + 3] = v.w;
  }
  __syncthreads();
  ushort* dst = xT + (size_t)b * 4096 * 512;
#pragma unroll
  for (int q = 0; q < 2; ++q) {
    int ch = t + 256 * q;
    int nl = ch >> 3;
    int cf = (ch & 7) * 8;
    uint4 o;
    o.x = pack2bf(tile[cf + 0][nl], tile[cf + 1][nl]);
    o.y = pack2bf(tile[cf + 2][nl], tile[cf + 3][nl]);
    o.z = pack2bf(tile[cf + 4][nl], tile[cf + 5][nl]);
    o.w = pack2bf(tile[cf + 6][nl], tile[cf + 7][nl]);
    *reinterpret_cast<uint4*>(dst + (size_t)(n0 + nl) * 512 + c0 + cf) = o;
  }
}

// ---------- kernel 3: projection GEMM [640 x 4096, K=512] per batch ----------
__global__ __launch_bounds__(256) void k_proj(const ushort* __restrict__ Wcat, const float* __restrict__ bcat,
                                              const ushort* __restrict__ xT, ushort* __restrict__ bT,
                                              ushort* __restrict__ cT, ushort* __restrict__ dmat) {
  int bx = blockIdx.x;
  int b = bx / 160;
  int r = bx % 160;
  int m0 = (r >> 5) * 128;    // 5 m-tiles
  int n0 = (r & 31) * 128;    // 32 n-tiles
  int t = threadIdx.x, l = t & 63, w = t >> 6;
  int wm = w >> 1, wn = w & 1, g = l >> 4, l15 = l & 15;
  const ushort* xb = xT + (size_t)b * 4096 * 512;
  f32x4 acc[4][4] = {};
  s16x8 bfn[4];
#pragma unroll
  for (int nt = 0; nt < 4; ++nt)
    bfn[nt] = *reinterpret_cast<const s16x8*>(xb + (size_t)(n0 + 64 * wn + 16 * nt + l15) * 512 + 8 * g);
  for (int k0 = 0; k0 < 512; k0 += 32) {
    s16x8 a[4], bf[4];
#pragma unroll
    for (int nt = 0; nt < 4; ++nt) bf[nt] = bfn[nt];
#pragma unroll
    for (int mt = 0; mt < 4; ++mt)
      a[mt] = *reinterpret_cast<const s16x8*>(Wcat + (size_t)(m0 + 64 * wm + 16 * mt + l15) * 512 + k0 + 8 * g);
    if (k0 + 32 < 512) {
#pragma unroll
      for (int nt = 0; nt < 4; ++nt)
        bfn[nt] = *reinterpret_cast<const s16x8*>(xb + (size_t)(n0 + 64 * wn + 16 * nt + l15) * 512 + k0 + 32 + 8 * g);
    }
#pragma unroll
    for (int mt = 0; mt < 4; ++mt)
#pragma unroll
      for (int nt = 0; nt < 4; ++nt)
        acc[mt][nt] = MFMA_BF16(a[mt], bf[nt], acc[mt][nt]);
  }
#pragma unroll
  for (int mt = 0; mt < 4; ++mt) {
    int mbase = m0 + 64 * wm + 16 * mt + 4 * g;
#pragma unroll
    for (int nt = 0; nt < 4; ++nt) {
      int n = n0 + 64 * wn + 16 * nt + l15;
      float v0 = acc[mt][nt][0] + bcat[mbase + 0];
      float v1 = acc[mt][nt][1] + bcat[mbase + 1];
      float v2 = acc[mt][nt][2] + bcat[mbase + 2];
      float v3 = acc[mt][nt][3] + bcat[mbase + 3];
      if (mbase < 64) {
        uint2 u; u.x = pack2bf(v0, v1); u.y = pack2bf(v2, v3);
        *reinterpret_cast<uint2*>(bT + ((size_t)b * 4096 + n) * 64 + mbase) = u;
      } else if (mbase < 128) {
        uint2 u; u.x = pack2bf(v0, v1); u.y = pack2bf(v2, v3);
        *reinterpret_cast<uint2*>(cT + ((size_t)b * 4096 + n) * 64 + (mbase - 64)) = u;
      } else {
        size_t base = ((size_t)b * 512 + (mbase - 128)) * 4096 + n;
        dmat[base + 0 * 4096] = f2bf(v0);
        dmat[base + 1 * 4096] = f2bf(v1);
        dmat[base + 2 * 4096] = f2bf(v2);
        dmat[base + 3 * 4096] = f2bf(v3);
      }
    }
  }
}

// ---------- kernel 4: stats + fold  d[c,i] *= 1/sum_j exp(s_ij - 30) ----------
__global__ __launch_bounds__(512) void k_stats(const ushort* __restrict__ bT, const ushort* __restrict__ cT,
                                               ushort* __restrict__ dmat) {
  __shared__ float lsum[64];
  int bx = blockIdx.x;
  int b = bx >> 6;
  int i0 = (bx & 63) * 64;
  int t = threadIdx.x, l = t & 63, w = t >> 6;
  int wm = w >> 1, wn = w & 1, g = l >> 4, l15 = l & 15;
  if (t < 64) lsum[t] = 0.f;
  __syncthreads();
  const ushort* bTb = bT + (size_t)b * 4096 * 64;
  const ushort* cTb = cT + (size_t)b * 4096 * 64;
  const ushort* ar = bTb + (size_t)(i0 + 16 * wm + l15) * 64 + 8 * g;
  s16x8 a0 = *reinterpret_cast<const s16x8*>(ar);
  s16x8 a1 = *reinterpret_cast<const s16x8*>(ar + 32);
  float lacc[4] = {0.f, 0.f, 0.f, 0.f};
  s16x8 b0n[4], b1n[4];
#pragma unroll
  for (int nt = 0; nt < 4; ++nt) {
    const ushort* cr = cTb + (size_t)(64 * wn + 16 * nt + l15) * 64 + 8 * g;
    b0n[nt] = *reinterpret_cast<const s16x8*>(cr);
    b1n[nt] = *reinterpret_cast<const s16x8*>(cr + 32);
  }
  for (int it = 0; it < 32; ++it) {
    s16x8 b0[4], b1[4];
#pragma unroll
    for (int nt = 0; nt < 4; ++nt) { b0[nt] = b0n[nt]; b1[nt] = b1n[nt]; }
    if (it + 1 < 32) {
      int jb = 64 * wn + 128 * (it + 1);
#pragma unroll
      for (int nt = 0; nt < 4; ++nt) {
        const ushort* cr = cTb + (size_t)(jb + 16 * nt + l15) * 64 + 8 * g;
        b0n[nt] = *reinterpret_cast<const s16x8*>(cr);
        b1n[nt] = *reinterpret_cast<const s16x8*>(cr + 32);
      }
    }
#pragma unroll
    for (int nt = 0; nt < 4; ++nt) {
      f32x4 s = {0.f, 0.f, 0.f, 0.f};
      s = MFMA_BF16(a0, b0[nt], s);
      s = MFMA_BF16(a1, b1[nt], s);
#pragma unroll
      for (int rr = 0; rr < 4; ++rr) lacc[rr] += pexp(s[rr]);
    }
  }
#pragma unroll
  for (int off = 1; off < 16; off <<= 1)
#pragma unroll
    for (int rr = 0; rr < 4; ++rr) lacc[rr] += __shfl_xor(lacc[rr], off);
  if (l15 == 0) {
#pragma unroll
    for (int rr = 0; rr < 4; ++rr) atomicAdd(&lsum[16 * wm + 4 * g + rr], lacc[rr]);
  }
  __syncthreads();
  if (t < 64) lsum[t] = 1.0f / fmaxf(lsum[t], 1e-30f);
  __syncthreads();
  ushort* drow = dmat + ((size_t)b * 512 + t) * 4096 + i0;
#pragma unroll
  for (int q = 0; q < 8; ++q) {
    s16x8 v = *reinterpret_cast<s16x8*>(drow + q * 8);
    s16x8 nv;
#pragma unroll
    for (int e = 0; e < 8; ++e) {
      float f = __builtin_bit_cast(float, ((uint)(ushort)v[e]) << 16) * lsum[q * 8 + e];
      nv[e] = (short)f2bf(f);
    }
    *reinterpret_cast<s16x8*>(drow + q * 8) = nv;
  }
}

// ---------- kernel 5: fused  Y = d' . exp(S-30) ; out = x + Y ----------
// Wave-independent, zero barriers, zero LDS. Each wave: (b, 64 c-rows, 32 j-cols).
// ALL global loads (bT and d fragments) double-buffered one i-step ahead ->
// no same-iteration load->use dependency. XCD swizzle groups the 128 waves
// sharing one (b, c-block) d-panel onto one XCD's L2.
__global__ __launch_bounds__(256, 2) void k_attn(const ushort* __restrict__ bT, const ushort* __restrict__ cT,
                                                 const ushort* __restrict__ dmat,
                                                 const float* __restrict__ x, float* __restrict__ out) {
  int bid = blockIdx.x;                       // 1024 blocks
  int swz = (bid & 7) * 128 + (bid >> 3);     // bijective XCD grouping
  int wid = swz * 4 + (threadIdx.x >> 6);     // 0..4095
  int l = threadIdx.x & 63;
  int l31 = l & 31, hi = l >> 5;
  int b  = wid >> 10;           // 1024 wave-jobs per batch
  int cb = (wid >> 7) & 7;      // 8 c-blocks of 64
  int jb = wid & 127;           // 128 j-blocks of 32
  int c0 = cb * 64, j0 = jb * 32;
  const ushort* bTb = bT + (size_t)b * 4096 * 64;
  const ushort* cTb = cT + (size_t)b * 4096 * 64;
  const ushort* db  = dmat + (size_t)b * 512 * 4096;

  // cT fragments (fixed): lane n=j=l31, k = 16*kc + 8*hi + [0,8)
  s16x8 cf[4];
#pragma unroll
  for (int kc = 0; kc < 4; ++kc)
    cf[kc] = *reinterpret_cast<const s16x8*>(cTb + (size_t)(j0 + l31) * 64 + kc * 16 + hi * 8);

  const ushort* brow = bTb + (size_t)l31 * 64 + hi * 8;
  const ushort* drow = db + (size_t)(c0 + l31) * 4096 + hi * 8;

  // prefetch i0=0 operands
  s16x8 bfn[4];
#pragma unroll
  for (int kc = 0; kc < 4; ++kc)
    bfn[kc] = *reinterpret_cast<const s16x8*>(brow + kc * 16);
  s16x8 dfn[2][2];
#pragma unroll
  for (int ch = 0; ch < 2; ++ch)
#pragma unroll
    for (int ct = 0; ct < 2; ++ct)
      dfn[ch][ct] = *reinterpret_cast<const s16x8*>(drow + (size_t)ct * 32 * 4096 + ch * 16);

  f32x16 zero16;
#pragma unroll
  for (int r = 0; r < 16; ++r) zero16[r] = 0.f;
  f32x16 yacc[2];
  yacc[0] = zero16; yacc[1] = zero16;

  for (int i0 = 0; i0 < 4096; i0 += 32) {
    s16x8 bf[4];
#pragma unroll
    for (int kc = 0; kc < 4; ++kc) bf[kc] = bfn[kc];
    s16x8 df[2][2];
#pragma unroll
    for (int ch = 0; ch < 2; ++ch)
#pragma unroll
      for (int ct = 0; ct < 2; ++ct) df[ch][ct] = dfn[ch][ct];
    // prefetch next i-step (wraps harmlessly on last iter)
    int inext = (i0 + 32) & 4095;
#pragma unroll
    for (int kc = 0; kc < 4; ++kc)
      bfn[kc] = *reinterpret_cast<const s16x8*>(brow + (size_t)inext * 64 + kc * 16);
#pragma unroll
    for (int ch = 0; ch < 2; ++ch)
#pragma unroll
      for (int ct = 0; ct < 2; ++ct)
        dfn[ch][ct] = *reinterpret_cast<const s16x8*>(drow + (size_t)ct * 32 * 4096 + inext + ch * 16);
    // scores S[32 i][32 j], K=64: D col=j=l31, row=i=(r&3)+8*(r>>2)+4*hi
    f32x16 s = zero16;
#pragma unroll
    for (int kc = 0; kc < 4; ++kc) s = MFMA32(bf[kc], cf[kc], s);
    float p[16];
#pragma unroll
    for (int r = 0; r < 16; ++r) p[r] = pexp(s[r]);
    // pack to PV B-operand: lane (j=l31, hi) gets P[i0 + 16*ch + 8*hi + t][j]
    uint x0 = cvtpk(p[0], p[1]),   y0 = cvtpk(p[4], p[5]);
    uint x1 = cvtpk(p[2], p[3]),   y1 = cvtpk(p[6], p[7]);
    uint x2 = cvtpk(p[8], p[9]),   y2 = cvtpk(p[12], p[13]);
    uint x3 = cvtpk(p[10], p[11]), y3 = cvtpk(p[14], p[15]);
    plswap(x0, y0); plswap(x1, y1); plswap(x2, y2); plswap(x3, y3);
    u32x4 pw0 = {x0, x1, y0, y1};
    u32x4 pw1 = {x2, x3, y2, y3};
    s16x8 pf0 = __builtin_bit_cast(s16x8, pw0);
    s16x8 pf1 = __builtin_bit_cast(s16x8, pw1);
    // PV: Y[c, j] += d'[c, i] * P[i, j]
#pragma unroll
    for (int ct = 0; ct < 2; ++ct) {
      yacc[ct] = MFMA32(df[0][ct], pf0, yacc[ct]);
      yacc[ct] = MFMA32(df[1][ct], pf1, yacc[ct]);
    }
  }
  // epilogue: out = x + Y
#pragma unroll
  for (int ct = 0; ct < 2; ++ct) {
#pragma unroll
    for (int r = 0; r < 16; ++r) {
      int row = c0 + 32 * ct + (r & 3) + 8 * (r >> 2) + 4 * hi;
      size_t idx = ((size_t)b * 512 + row) * 4096 + j0 + l31;
      out[idx] = x[idx] + yacc[ct][r];
    }
  }
}

extern "C" void kernel_launch(void* const* d_in, const int* in_sizes, int n_in,
                              void* d_out, int out_size, void* d_ws, size_t ws_size,
                              hipStream_t stream) {
  const float* x  = (const float*)d_in[0];
  const float* Wb = (const float*)d_in[1];
  const float* bb = (const float*)d_in[2];
  const float* Wc = (const float*)d_in[3];
  const float* bc = (const float*)d_in[4];
  const float* Wd = (const float*)d_in[5];
  const float* bd = (const float*)d_in[6];
  char* ws = (char*)d_ws;
  ushort* xT   = (ushort*)(ws + WS_XT);
  ushort* dmat = (ushort*)(ws + WS_D);
  ushort* bT   = (ushort*)(ws + WS_BT);
  ushort* cT   = (ushort*)(ws + WS_CT);
  ushort* Wcat = (ushort*)(ws + WS_WCAT);
  float*  bcat = (float*)(ws + WS_BCAT);
  float*  out  = (float*)d_out;

  k_prep_w<<<1280, 256, 0, stream>>>(Wb, bb, Wc, bc, Wd, bd, Wcat, bcat);
  k_prep_xt<<<2048, 256, 0, stream>>>(x, xT);
  k_proj<<<640, 256, 0, stream>>>(Wcat, bcat, xT, bT, cT, dmat);
  k_stats<<<256, 512, 0, stream>>>(bT, cT, dmat);
  k_attn<<<1024, 256, 0, stream>>>(bT, cT, dmat, x, out);
}

// Round 5
// 478.084 us; speedup vs baseline: 1.2292x; 1.2292x over previous
//
#include <hip/hip_runtime.h>
#include <hip/hip_bf16.h>

typedef float f32x4 __attribute__((ext_vector_type(4)));
typedef float f32x16 __attribute__((ext_vector_type(16)));
typedef short s16x8 __attribute__((ext_vector_type(8)));
typedef uint  u32x4 __attribute__((ext_vector_type(4)));

#define MFMA_BF16(a, b, c) __builtin_amdgcn_mfma_f32_16x16x32_bf16((a), (b), (c), 0, 0, 0)
#define MFMA32(a, b, c)    __builtin_amdgcn_mfma_f32_32x32x16_bf16((a), (b), (c), 0, 0, 0)

// ---------- helpers ----------
__device__ __forceinline__ ushort f2bf(float f) {
  uint u = __builtin_bit_cast(uint, f);
  u += 0x7FFFu + ((u >> 16) & 1u);
  return (ushort)(u >> 16);
}
__device__ __forceinline__ uint pack2bf(float a, float b) {
  return (uint)f2bf(a) | ((uint)f2bf(b) << 16);
}
// exp(s - 30) written identically in stats and attn kernels
__device__ __forceinline__ float pexp(float s) {
  return exp2f(fmaf(s, 1.4426950408889634f, -43.2808512266689f));
}
__device__ __forceinline__ uint cvtpk(float lo, float hi) {
  uint r;
  asm("v_cvt_pk_bf16_f32 %0, %1, %2" : "=v"(r) : "v"(lo), "v"(hi));
  return r;
}
__device__ __forceinline__ void plswap(uint& a, uint& b) {
  asm("v_permlane32_swap_b32 %0, %1" : "+v"(a), "+v"(b));
}

// ---------- ws layout (bytes) ----------
#define WS_XT    0UL
#define WS_D     16777216UL
#define WS_BT    33554432UL
#define WS_CT    35651584UL
#define WS_WCAT  37748736UL
#define WS_BCAT  38404096UL

// ---------- kernel 1: pack weights to bf16 [640][512] + bias concat ----------
__global__ void k_prep_w(const float* __restrict__ Wb, const float* __restrict__ bb,
                         const float* __restrict__ Wc, const float* __restrict__ bc,
                         const float* __restrict__ Wd, const float* __restrict__ bd,
                         ushort* __restrict__ Wcat, float* __restrict__ bcat) {
  int idx = blockIdx.x * 256 + threadIdx.x;
  if (idx < 640 * 512) {
    int m = idx >> 9, k = idx & 511;
    float v = (m < 64) ? Wb[m * 512 + k] : (m < 128) ? Wc[(m - 64) * 512 + k] : Wd[(m - 128) * 512 + k];
    Wcat[idx] = f2bf(v);
  }
  if (idx < 640) {
    bcat[idx] = (idx < 64) ? bb[idx] : (idx < 128) ? bc[idx - 64] : bd[idx - 128];
  }
}

// ---------- kernel 2: transpose x [B][512][4096] f32 -> xT [B][4096][512] bf16 ----------
__global__ __launch_bounds__(256) void k_prep_xt(const float* __restrict__ x, ushort* __restrict__ xT) {
  __shared__ float tile[64][65];
  int bx = blockIdx.x;
  int b = bx >> 9;                  // 8*64 = 512 tiles per batch
  int c0 = ((bx >> 6) & 7) * 64;
  int n0 = (bx & 63) * 64;
  int t = threadIdx.x;
  const float* xb = x + (size_t)b * 512 * 4096;
#pragma unroll
  for (int p = 0; p < 4; ++p) {
    int cl = (t >> 4) + 16 * p;
    int nf = (t & 15) * 4;
    float4 v = *reinterpret_cast<const float4*>(xb + (size_t)(c0 + cl) * 4096 + n0 + nf);
    tile[cl][nf + 0] = v.x; tile[cl][nf + 1] = v.y; tile[cl][nf + 2] = v.z; tile[cl][nf + 3] = v.w;
  }
  __syncthreads();
  ushort* dst = xT + (size_t)b * 4096 * 512;
#pragma unroll
  for (int q = 0; q < 2; ++q) {
    int ch = t + 256 * q;
    int nl = ch >> 3;
    int cf = (ch & 7) * 8;
    uint4 o;
    o.x = pack2bf(tile[cf + 0][nl], tile[cf + 1][nl]);
    o.y = pack2bf(tile[cf + 2][nl], tile[cf + 3][nl]);
    o.z = pack2bf(tile[cf + 4][nl], tile[cf + 5][nl]);
    o.w = pack2bf(tile[cf + 6][nl], tile[cf + 7][nl]);
    *reinterpret_cast<uint4*>(dst + (size_t)(n0 + nl) * 512 + c0 + cf) = o;
  }
}

// ---------- kernel 3: projection GEMM [640 x 4096, K=512] per batch ----------
__global__ __launch_bounds__(256) void k_proj(const ushort* __restrict__ Wcat, const float* __restrict__ bcat,
                                              const ushort* __restrict__ xT, ushort* __restrict__ bT,
                                              ushort* __restrict__ cT, ushort* __restrict__ dmat) {
  int bx = blockIdx.x;
  int b = bx / 160;
  int r = bx % 160;
  int m0 = (r >> 5) * 128;    // 5 m-tiles
  int n0 = (r & 31) * 128;    // 32 n-tiles
  int t = threadIdx.x, l = t & 63, w = t >> 6;
  int wm = w >> 1, wn = w & 1, g = l >> 4, l15 = l & 15;
  const ushort* xb = xT + (size_t)b * 4096 * 512;
  f32x4 acc[4][4] = {};
  s16x8 bfn[4];
#pragma unroll
  for (int nt = 0; nt < 4; ++nt)
    bfn[nt] = *reinterpret_cast<const s16x8*>(xb + (size_t)(n0 + 64 * wn + 16 * nt + l15) * 512 + 8 * g);
  for (int k0 = 0; k0 < 512; k0 += 32) {
    s16x8 a[4], bf[4];
#pragma unroll
    for (int nt = 0; nt < 4; ++nt) bf[nt] = bfn[nt];
#pragma unroll
    for (int mt = 0; mt < 4; ++mt)
      a[mt] = *reinterpret_cast<const s16x8*>(Wcat + (size_t)(m0 + 64 * wm + 16 * mt + l15) * 512 + k0 + 8 * g);
    if (k0 + 32 < 512) {
#pragma unroll
      for (int nt = 0; nt < 4; ++nt)
        bfn[nt] = *reinterpret_cast<const s16x8*>(xb + (size_t)(n0 + 64 * wn + 16 * nt + l15) * 512 + k0 + 32 + 8 * g);
    }
    __builtin_amdgcn_sched_barrier(0);
#pragma unroll
    for (int mt = 0; mt < 4; ++mt)
#pragma unroll
      for (int nt = 0; nt < 4; ++nt)
        acc[mt][nt] = MFMA_BF16(a[mt], bf[nt], acc[mt][nt]);
  }
#pragma unroll
  for (int mt = 0; mt < 4; ++mt) {
    int mbase = m0 + 64 * wm + 16 * mt + 4 * g;
#pragma unroll
    for (int nt = 0; nt < 4; ++nt) {
      int n = n0 + 64 * wn + 16 * nt + l15;
      float v0 = acc[mt][nt][0] + bcat[mbase + 0];
      float v1 = acc[mt][nt][1] + bcat[mbase + 1];
      float v2 = acc[mt][nt][2] + bcat[mbase + 2];
      float v3 = acc[mt][nt][3] + bcat[mbase + 3];
      if (mbase < 64) {
        uint2 u; u.x = pack2bf(v0, v1); u.y = pack2bf(v2, v3);
        *reinterpret_cast<uint2*>(bT + ((size_t)b * 4096 + n) * 64 + mbase) = u;
      } else if (mbase < 128) {
        uint2 u; u.x = pack2bf(v0, v1); u.y = pack2bf(v2, v3);
        *reinterpret_cast<uint2*>(cT + ((size_t)b * 4096 + n) * 64 + (mbase - 64)) = u;
      } else {
        size_t base = ((size_t)b * 512 + (mbase - 128)) * 4096 + n;
        dmat[base + 0 * 4096] = f2bf(v0);
        dmat[base + 1 * 4096] = f2bf(v1);
        dmat[base + 2 * 4096] = f2bf(v2);
        dmat[base + 3 * 4096] = f2bf(v3);
      }
    }
  }
}

// ---------- kernel 4: stats + fold  d[c,i] *= 1/sum_j exp(s_ij - 30) ----------
__global__ __launch_bounds__(512) void k_stats(const ushort* __restrict__ bT, const ushort* __restrict__ cT,
                                               ushort* __restrict__ dmat) {
  __shared__ float lsum[64];
  int bx = blockIdx.x;
  int b = bx >> 6;
  int i0 = (bx & 63) * 64;
  int t = threadIdx.x, l = t & 63, w = t >> 6;
  int wm = w >> 1, wn = w & 1, g = l >> 4, l15 = l & 15;
  if (t < 64) lsum[t] = 0.f;
  __syncthreads();
  const ushort* bTb = bT + (size_t)b * 4096 * 64;
  const ushort* cTb = cT + (size_t)b * 4096 * 64;
  const ushort* ar = bTb + (size_t)(i0 + 16 * wm + l15) * 64 + 8 * g;
  s16x8 a0 = *reinterpret_cast<const s16x8*>(ar);
  s16x8 a1 = *reinterpret_cast<const s16x8*>(ar + 32);
  float lacc[4] = {0.f, 0.f, 0.f, 0.f};
  s16x8 b0n[4], b1n[4];
#pragma unroll
  for (int nt = 0; nt < 4; ++nt) {
    const ushort* cr = cTb + (size_t)(64 * wn + 16 * nt + l15) * 64 + 8 * g;
    b0n[nt] = *reinterpret_cast<const s16x8*>(cr);
    b1n[nt] = *reinterpret_cast<const s16x8*>(cr + 32);
  }
  for (int it = 0; it < 32; ++it) {
    s16x8 b0[4], b1[4];
#pragma unroll
    for (int nt = 0; nt < 4; ++nt) { b0[nt] = b0n[nt]; b1[nt] = b1n[nt]; }
    if (it + 1 < 32) {
      int jb = 64 * wn + 128 * (it + 1);
#pragma unroll
      for (int nt = 0; nt < 4; ++nt) {
        const ushort* cr = cTb + (size_t)(jb + 16 * nt + l15) * 64 + 8 * g;
        b0n[nt] = *reinterpret_cast<const s16x8*>(cr);
        b1n[nt] = *reinterpret_cast<const s16x8*>(cr + 32);
      }
    }
    __builtin_amdgcn_sched_barrier(0);
#pragma unroll
    for (int nt = 0; nt < 4; ++nt) {
      f32x4 s = {0.f, 0.f, 0.f, 0.f};
      s = MFMA_BF16(a0, b0[nt], s);
      s = MFMA_BF16(a1, b1[nt], s);
#pragma unroll
      for (int rr = 0; rr < 4; ++rr) lacc[rr] += pexp(s[rr]);
    }
  }
#pragma unroll
  for (int off = 1; off < 16; off <<= 1)
#pragma unroll
    for (int rr = 0; rr < 4; ++rr) lacc[rr] += __shfl_xor(lacc[rr], off);
  if (l15 == 0) {
#pragma unroll
    for (int rr = 0; rr < 4; ++rr) atomicAdd(&lsum[16 * wm + 4 * g + rr], lacc[rr]);
  }
  __syncthreads();
  if (t < 64) lsum[t] = 1.0f / fmaxf(lsum[t], 1e-30f);
  __syncthreads();
  ushort* drow = dmat + ((size_t)b * 512 + t) * 4096 + i0;
#pragma unroll
  for (int q = 0; q < 8; ++q) {
    s16x8 v = *reinterpret_cast<s16x8*>(drow + q * 8);
    s16x8 nv;
#pragma unroll
    for (int e = 0; e < 8; ++e) {
      float f = __builtin_bit_cast(float, ((uint)(ushort)v[e]) << 16) * lsum[q * 8 + e];
      nv[e] = (short)f2bf(f);
    }
    *reinterpret_cast<s16x8*>(drow + q * 8) = nv;
  }
}

// ---------- kernel 5: fused  Y = d' . exp(S-30) ; out = x + Y ----------
// Wave-independent, zero barriers, zero LDS. Each wave: (b, 128 c-rows, 32 j-cols).
// Double-buffered bT/d loads PINNED before compute via sched_barrier(0) so the
// compiler cannot sink them to the loop bottom (round-4 failure: VGPR=48 proved
// the prefetch was defeated). XCD swizzle keeps each (b,c-block) d-panel on one
// XCD's L2 (round 4: FETCH_SIZE 91->28.7 GB).
__global__ __launch_bounds__(256, 2) void k_attn(const ushort* __restrict__ bT, const ushort* __restrict__ cT,
                                                 const ushort* __restrict__ dmat,
                                                 const float* __restrict__ x, float* __restrict__ out) {
  int bid = blockIdx.x;                       // 512 blocks
  int swz = (bid & 7) * 64 + (bid >> 3);      // bijective; 64 consecutive jobs per XCD
  int wid = swz * 4 + (threadIdx.x >> 6);     // 0..2047
  int l = threadIdx.x & 63;
  int l31 = l & 31, hi = l >> 5;
  int b  = wid >> 9;            // 512 wave-jobs per batch
  int cb = (wid >> 7) & 3;      // 4 c-blocks of 128
  int jb = wid & 127;           // 128 j-blocks of 32
  int c0 = cb * 128, j0 = jb * 32;
  const ushort* bTb = bT + (size_t)b * 4096 * 64;
  const ushort* cTb = cT + (size_t)b * 4096 * 64;
  const ushort* db  = dmat + (size_t)b * 512 * 4096;

  // cT fragments (fixed): lane n=j=l31, k = 16*kc + 8*hi + [0,8)
  s16x8 cf[4];
#pragma unroll
  for (int kc = 0; kc < 4; ++kc)
    cf[kc] = *reinterpret_cast<const s16x8*>(cTb + (size_t)(j0 + l31) * 64 + kc * 16 + hi * 8);

  const ushort* brow = bTb + (size_t)l31 * 64 + hi * 8;
  const ushort* drow = db + (size_t)(c0 + l31) * 4096 + hi * 8;

  // prefetch i0=0 operands
  s16x8 bfn[4];
#pragma unroll
  for (int kc = 0; kc < 4; ++kc)
    bfn[kc] = *reinterpret_cast<const s16x8*>(brow + kc * 16);
  s16x8 dfn[2][4];
#pragma unroll
  for (int ch = 0; ch < 2; ++ch)
#pragma unroll
    for (int ct = 0; ct < 4; ++ct)
      dfn[ch][ct] = *reinterpret_cast<const s16x8*>(drow + (size_t)ct * 32 * 4096 + ch * 16);

  f32x16 zero16;
#pragma unroll
  for (int r = 0; r < 16; ++r) zero16[r] = 0.f;
  f32x16 yacc[4];
#pragma unroll
  for (int ct = 0; ct < 4; ++ct) yacc[ct] = zero16;

  for (int i0 = 0; i0 < 4096; i0 += 32) {
    // rotate pipeline registers
    s16x8 bf[4];
#pragma unroll
    for (int kc = 0; kc < 4; ++kc) bf[kc] = bfn[kc];
    s16x8 df[2][4];
#pragma unroll
    for (int ch = 0; ch < 2; ++ch)
#pragma unroll
      for (int ct = 0; ct < 4; ++ct) df[ch][ct] = dfn[ch][ct];
    // issue next i-step's loads (wraps harmlessly on last iter)
    int inext = (i0 + 32) & 4095;
#pragma unroll
    for (int kc = 0; kc < 4; ++kc)
      bfn[kc] = *reinterpret_cast<const s16x8*>(brow + (size_t)inext * 64 + kc * 16);
#pragma unroll
    for (int ch = 0; ch < 2; ++ch)
#pragma unroll
      for (int ct = 0; ct < 4; ++ct)
        dfn[ch][ct] = *reinterpret_cast<const s16x8*>(drow + (size_t)ct * 32 * 4096 + inext + ch * 16);
    // fence: loads may not sink below; compute may not hoist above
    __builtin_amdgcn_sched_barrier(0);
    // scores S[32 i][32 j], K=64: D col=j=l31, row=i=(r&3)+8*(r>>2)+4*hi
    f32x16 s = zero16;
#pragma unroll
    for (int kc = 0; kc < 4; ++kc) s = MFMA32(bf[kc], cf[kc], s);
    float p[16];
#pragma unroll
    for (int r = 0; r < 16; ++r) p[r] = pexp(s[r]);
    // pack to PV B-operand: lane (j=l31, hi) gets P[i0 + 16*ch + 8*hi + t][j]
    uint x0 = cvtpk(p[0], p[1]),   y0 = cvtpk(p[4], p[5]);
    uint x1 = cvtpk(p[2], p[3]),   y1 = cvtpk(p[6], p[7]);
    uint x2 = cvtpk(p[8], p[9]),   y2 = cvtpk(p[12], p[13]);
    uint x3 = cvtpk(p[10], p[11]), y3 = cvtpk(p[14], p[15]);
    plswap(x0, y0); plswap(x1, y1); plswap(x2, y2); plswap(x3, y3);
    u32x4 pw0 = {x0, x1, y0, y1};
    u32x4 pw1 = {x2, x3, y2, y3};
    s16x8 pf0 = __builtin_bit_cast(s16x8, pw0);
    s16x8 pf1 = __builtin_bit_cast(s16x8, pw1);
    // PV: Y[c, j] += d'[c, i] * P[i, j]
#pragma unroll
    for (int ct = 0; ct < 4; ++ct) {
      yacc[ct] = MFMA32(df[0][ct], pf0, yacc[ct]);
      yacc[ct] = MFMA32(df[1][ct], pf1, yacc[ct]);
    }
  }
  // epilogue: out = x + Y
#pragma unroll
  for (int ct = 0; ct < 4; ++ct) {
#pragma unroll
    for (int r = 0; r < 16; ++r) {
      int row = c0 + 32 * ct + (r & 3) + 8 * (r >> 2) + 4 * hi;
      size_t idx = ((size_t)b * 512 + row) * 4096 + j0 + l31;
      out[idx] = x[idx] + yacc[ct][r];
    }
  }
}

extern "C" void kernel_launch(void* const* d_in, const int* in_sizes, int n_in,
                              void* d_out, int out_size, void* d_ws, size_t ws_size,
                              hipStream_t stream) {
  const float* x  = (const float*)d_in[0];
  const float* Wb = (const float*)d_in[1];
  const float* bb = (const float*)d_in[2];
  const float* Wc = (const float*)d_in[3];
  const float* bc = (const float*)d_in[4];
  const float* Wd = (const float*)d_in[5];
  const float* bd = (const float*)d_in[6];
  char* ws = (char*)d_ws;
  ushort* xT   = (ushort*)(ws + WS_XT);
  ushort* dmat = (ushort*)(ws + WS_D);
  ushort* bT   = (ushort*)(ws + WS_BT);
  ushort* cT   = (ushort*)(ws + WS_CT);
  ushort* Wcat = (ushort*)(ws + WS_WCAT);
  float*  bcat = (float*)(ws + WS_BCAT);
  float*  out  = (float*)d_out;

  k_prep_w<<<1280, 256, 0, stream>>>(Wb, bb, Wc, bc, Wd, bd, Wcat, bcat);
  k_prep_xt<<<2048, 256, 0, stream>>>(x, xT);
  k_proj<<<640, 256, 0, stream>>>(Wcat, bcat, xT, bT, cT, dmat);
  k_stats<<<256, 512, 0, stream>>>(bT, cT, dmat);
  k_attn<<<512, 256, 0, stream>>>(bT, cT, dmat, x, out);
}

// Round 6
// 265.898 us; speedup vs baseline: 2.2100x; 1.7980x over previous
//
#include <hip/hip_runtime.h>
#include <hip/hip_bf16.h>

typedef float f32x4 __attribute__((ext_vector_type(4)));
typedef float f32x16 __attribute__((ext_vector_type(16)));
typedef short s16x8 __attribute__((ext_vector_type(8)));
typedef uint  u32x4 __attribute__((ext_vector_type(4)));

#define MFMA_BF16(a, b, c) __builtin_amdgcn_mfma_f32_16x16x32_bf16((a), (b), (c), 0, 0, 0)
#define MFMA32(a, b, c)    __builtin_amdgcn_mfma_f32_32x32x16_bf16((a), (b), (c), 0, 0, 0)

// ---------- helpers ----------
__device__ __forceinline__ ushort f2bf(float f) {
  uint u = __builtin_bit_cast(uint, f);
  u += 0x7FFFu + ((u >> 16) & 1u);
  return (ushort)(u >> 16);
}
__device__ __forceinline__ uint pack2bf(float a, float b) {
  return (uint)f2bf(a) | ((uint)f2bf(b) << 16);
}
// exp(s - 30) written identically in stats and attn kernels
__device__ __forceinline__ float pexp(float s) {
  return exp2f(fmaf(s, 1.4426950408889634f, -43.2808512266689f));
}
__device__ __forceinline__ uint cvtpk(float lo, float hi) {
  uint r;
  asm("v_cvt_pk_bf16_f32 %0, %1, %2" : "=v"(r) : "v"(lo), "v"(hi));
  return r;
}
__device__ __forceinline__ void plswap(uint& a, uint& b) {
  asm("v_permlane32_swap_b32 %0, %1" : "+v"(a), "+v"(b));
}
__device__ __forceinline__ void gld16(const void* g, void* l) {
  __builtin_amdgcn_global_load_lds(
      (const __attribute__((address_space(1))) unsigned int*)g,
      (__attribute__((address_space(3))) unsigned int*)l, 16, 0, 0);
}

// ---------- ws layout (bytes) ----------
// dmat is TILED: [b][cb=c>>7][it=i>>5][c&127][32 i] with 16B-unit swizzle u^=(c&3)
// bT rows are unit-swizzled: unit u at row i stored at u^(i&7)
#define WS_XT    0UL
#define WS_D     16777216UL
#define WS_BT    33554432UL
#define WS_CT    35651584UL
#define WS_WCAT  37748736UL
#define WS_BCAT  38404096UL

// ---------- kernel 1: pack weights to bf16 [640][512] + bias concat ----------
__global__ void k_prep_w(const float* __restrict__ Wb, const float* __restrict__ bb,
                         const float* __restrict__ Wc, const float* __restrict__ bc,
                         const float* __restrict__ Wd, const float* __restrict__ bd,
                         ushort* __restrict__ Wcat, float* __restrict__ bcat) {
  int idx = blockIdx.x * 256 + threadIdx.x;
  if (idx < 640 * 512) {
    int m = idx >> 9, k = idx & 511;
    float v = (m < 64) ? Wb[m * 512 + k] : (m < 128) ? Wc[(m - 64) * 512 + k] : Wd[(m - 128) * 512 + k];
    Wcat[idx] = f2bf(v);
  }
  if (idx < 640) {
    bcat[idx] = (idx < 64) ? bb[idx] : (idx < 128) ? bc[idx - 64] : bd[idx - 128];
  }
}

// ---------- kernel 2: transpose x [B][512][4096] f32 -> xT [B][4096][512] bf16 ----------
__global__ __launch_bounds__(256) void k_prep_xt(const float* __restrict__ x, ushort* __restrict__ xT) {
  __shared__ float tile[64][65];
  int bx = blockIdx.x;
  int b = bx >> 9;                  // 8*64 = 512 tiles per batch
  int c0 = ((bx >> 6) & 7) * 64;
  int n0 = (bx & 63) * 64;
  int t = threadIdx.x;
  const float* xb = x + (size_t)b * 512 * 4096;
#pragma unroll
  for (int p = 0; p < 4; ++p) {
    int cl = (t >> 4) + 16 * p;
    int nf = (t & 15) * 4;
    float4 v = *reinterpret_cast<const float4*>(xb + (size_t)(c0 + cl) * 4096 + n0 + nf);
    tile[cl][nf + 0] = v.x; tile[cl][nf + 1] = v.y; tile[cl][nf + 2] = v.z; tile[cl][nf + 3] = v.w;
  }
  __syncthreads();
  ushort* dst = xT + (size_t)b * 4096 * 512;
#pragma unroll
  for (int q = 0; q < 2; ++q) {
    int ch = t + 256 * q;
    int nl = ch >> 3;
    int cf = (ch & 7) * 8;
    uint4 o;
    o.x = pack2bf(tile[cf + 0][nl], tile[cf + 1][nl]);
    o.y = pack2bf(tile[cf + 2][nl], tile[cf + 3][nl]);
    o.z = pack2bf(tile[cf + 4][nl], tile[cf + 5][nl]);
    o.w = pack2bf(tile[cf + 6][nl], tile[cf + 7][nl]);
    *reinterpret_cast<uint4*>(dst + (size_t)(n0 + nl) * 512 + c0 + cf) = o;
  }
}

// ---------- kernel 3: projection GEMM [640 x 4096, K=512] per batch ----------
__global__ __launch_bounds__(256) void k_proj(const ushort* __restrict__ Wcat, const float* __restrict__ bcat,
                                              const ushort* __restrict__ xT, ushort* __restrict__ bT,
                                              ushort* __restrict__ cT, ushort* __restrict__ dmat) {
  int bx = blockIdx.x;
  int b = bx / 160;
  int r = bx % 160;
  int m0 = (r >> 5) * 128;    // 5 m-tiles
  int n0 = (r & 31) * 128;    // 32 n-tiles
  int t = threadIdx.x, l = t & 63, w = t >> 6;
  int wm = w >> 1, wn = w & 1, g = l >> 4, l15 = l & 15;
  const ushort* xb = xT + (size_t)b * 4096 * 512;
  f32x4 acc[4][4] = {};
  s16x8 bfn[4];
#pragma unroll
  for (int nt = 0; nt < 4; ++nt)
    bfn[nt] = *reinterpret_cast<const s16x8*>(xb + (size_t)(n0 + 64 * wn + 16 * nt + l15) * 512 + 8 * g);
  for (int k0 = 0; k0 < 512; k0 += 32) {
    s16x8 a[4], bf[4];
#pragma unroll
    for (int nt = 0; nt < 4; ++nt) bf[nt] = bfn[nt];
#pragma unroll
    for (int mt = 0; mt < 4; ++mt)
      a[mt] = *reinterpret_cast<const s16x8*>(Wcat + (size_t)(m0 + 64 * wm + 16 * mt + l15) * 512 + k0 + 8 * g);
    if (k0 + 32 < 512) {
#pragma unroll
      for (int nt = 0; nt < 4; ++nt)
        bfn[nt] = *reinterpret_cast<const s16x8*>(xb + (size_t)(n0 + 64 * wn + 16 * nt + l15) * 512 + k0 + 32 + 8 * g);
    }
    __builtin_amdgcn_sched_barrier(0);
#pragma unroll
    for (int mt = 0; mt < 4; ++mt)
#pragma unroll
      for (int nt = 0; nt < 4; ++nt)
        acc[mt][nt] = MFMA_BF16(a[mt], bf[nt], acc[mt][nt]);
  }
#pragma unroll
  for (int mt = 0; mt < 4; ++mt) {
    int mbase = m0 + 64 * wm + 16 * mt + 4 * g;
#pragma unroll
    for (int nt = 0; nt < 4; ++nt) {
      int n = n0 + 64 * wn + 16 * nt + l15;
      float v0 = acc[mt][nt][0] + bcat[mbase + 0];
      float v1 = acc[mt][nt][1] + bcat[mbase + 1];
      float v2 = acc[mt][nt][2] + bcat[mbase + 2];
      float v3 = acc[mt][nt][3] + bcat[mbase + 3];
      if (mbase < 64) {
        // bT swizzled: unit u=mbase>>3 stored at u^(n&7); mbase&4 selects 8B half
        uint2 u2; u2.x = pack2bf(v0, v1); u2.y = pack2bf(v2, v3);
        size_t off = ((size_t)b * 4096 + n) * 64 + (size_t)((((mbase >> 3) ^ (n & 7)) << 3) + (mbase & 4));
        *reinterpret_cast<uint2*>(bT + off) = u2;
      } else if (mbase < 128) {
        uint2 u2; u2.x = pack2bf(v0, v1); u2.y = pack2bf(v2, v3);
        *reinterpret_cast<uint2*>(cT + ((size_t)b * 4096 + n) * 64 + (mbase - 64)) = u2;
      } else {
        // d tiled+swizzled: [b][cc>>7][n>>5][c&127][unit^(c&3)][n&7]
        int cc = mbase - 128;            // multiple of 4; c = cc + rr, c&3 = rr
        int cl = cc & 127;
        int un = (n >> 3) & 3;
        size_t pan = (size_t)b * 2097152 + (size_t)(cc >> 7) * 524288 +
                     (size_t)(n >> 5) * 4096 + (size_t)(n & 7);
        dmat[pan + (size_t)(cl + 0) * 32 + ((un ^ 0) << 3)] = f2bf(v0);
        dmat[pan + (size_t)(cl + 1) * 32 + ((un ^ 1) << 3)] = f2bf(v1);
        dmat[pan + (size_t)(cl + 2) * 32 + ((un ^ 2) << 3)] = f2bf(v2);
        dmat[pan + (size_t)(cl + 3) * 32 + ((un ^ 3) << 3)] = f2bf(v3);
      }
    }
  }
}

// ---------- kernel 4: stats + fold  d[c,i] *= 1/sum_j exp(s_ij - 30) ----------
__global__ __launch_bounds__(512) void k_stats(const ushort* __restrict__ bT, const ushort* __restrict__ cT,
                                               ushort* __restrict__ dmat) {
  __shared__ float lsum[64];
  int bx = blockIdx.x;
  int b = bx >> 6;
  int i0 = (bx & 63) * 64;
  int t = threadIdx.x, l = t & 63, w = t >> 6;
  int wm = w >> 1, wn = w & 1, g = l >> 4, l15 = l & 15;
  if (t < 64) lsum[t] = 0.f;
  __syncthreads();
  const ushort* bTb = bT + (size_t)b * 4096 * 64;
  const ushort* cTb = cT + (size_t)b * 4096 * 64;
  int arow = i0 + 16 * wm + l15;
  int r7 = arow & 7;
  const ushort* abase = bTb + (size_t)arow * 64;
  s16x8 a0 = *reinterpret_cast<const s16x8*>(abase + ((g ^ r7) << 3));
  s16x8 a1 = *reinterpret_cast<const s16x8*>(abase + (((g + 4) ^ r7) << 3));
  float lacc[4] = {0.f, 0.f, 0.f, 0.f};
  s16x8 b0n[4], b1n[4];
#pragma unroll
  for (int nt = 0; nt < 4; ++nt) {
    const ushort* cr = cTb + (size_t)(64 * wn + 16 * nt + l15) * 64 + 8 * g;
    b0n[nt] = *reinterpret_cast<const s16x8*>(cr);
    b1n[nt] = *reinterpret_cast<const s16x8*>(cr + 32);
  }
  for (int it = 0; it < 32; ++it) {
    s16x8 b0[4], b1[4];
#pragma unroll
    for (int nt = 0; nt < 4; ++nt) { b0[nt] = b0n[nt]; b1[nt] = b1n[nt]; }
    if (it + 1 < 32) {
      int jb = 64 * wn + 128 * (it + 1);
#pragma unroll
      for (int nt = 0; nt < 4; ++nt) {
        const ushort* cr = cTb + (size_t)(jb + 16 * nt + l15) * 64 + 8 * g;
        b0n[nt] = *reinterpret_cast<const s16x8*>(cr);
        b1n[nt] = *reinterpret_cast<const s16x8*>(cr + 32);
      }
    }
    __builtin_amdgcn_sched_barrier(0);
#pragma unroll
    for (int nt = 0; nt < 4; ++nt) {
      f32x4 s = {0.f, 0.f, 0.f, 0.f};
      s = MFMA_BF16(a0, b0[nt], s);
      s = MFMA_BF16(a1, b1[nt], s);
#pragma unroll
      for (int rr = 0; rr < 4; ++rr) lacc[rr] += pexp(s[rr]);
    }
  }
#pragma unroll
  for (int off = 1; off < 16; off <<= 1)
#pragma unroll
    for (int rr = 0; rr < 4; ++rr) lacc[rr] += __shfl_xor(lacc[rr], off);
  if (l15 == 0) {
#pragma unroll
    for (int rr = 0; rr < 4; ++rr) atomicAdd(&lsum[16 * wm + 4 * g + rr], lacc[rr]);
  }
  __syncthreads();
  if (t < 64) lsum[t] = 1.0f / fmaxf(lsum[t], 1e-30f);
  __syncthreads();
  // rescale dmat rows (tiled+swizzled layout), cols [i0, i0+64)
  ushort* dbase = dmat + (size_t)b * 2097152 + (size_t)(t >> 7) * 524288 + (size_t)(t & 127) * 32;
  int t3 = t & 3;
#pragma unroll
  for (int q = 0; q < 8; ++q) {
    size_t off = (size_t)((i0 >> 5) + (q >> 2)) * 4096 + (size_t)(((q & 3) ^ t3) << 3);
    s16x8 v = *reinterpret_cast<s16x8*>(dbase + off);
    s16x8 nv;
#pragma unroll
    for (int e = 0; e < 8; ++e) {
      float f = __builtin_bit_cast(float, ((uint)(ushort)v[e]) << 16) * lsum[q * 8 + e];
      nv[e] = (short)f2bf(f);
    }
    *reinterpret_cast<s16x8*>(dbase + off) = nv;
  }
}

// ---------- kernel 5: fused  Y = d' . exp(S-30) ; out = x + Y ----------
// Block = 4 waves, tile (b, 128 c, 128 j); wave w owns j-sub of 32. i-step 64.
// bT tile (8KB) + d tile (16KB) staged to LDS via global_load_lds (coalesced,
// double-buffered, loads issued before compute, one barrier/iter). Fragment
// reads are conflict-free via source-side XOR swizzle baked into k_proj.
__global__ __launch_bounds__(256, 2) void k_attn(const ushort* __restrict__ bT, const ushort* __restrict__ cT,
                                                 const ushort* __restrict__ dmat,
                                                 const float* __restrict__ x, float* __restrict__ out) {
  __shared__ ushort lds2[2][12288];           // [buf][ bf 8KB=4096 | df 16KB=8192 ]
  int bid = blockIdx.x;                       // 512 blocks, 2/CU
  int swz = (bid & 7) * 64 + (bid >> 3);      // XCD grouping: 64 consecutive jobs/XCD
  int b  = swz >> 7;
  int cb = (swz >> 5) & 3;
  int jB = swz & 31;
  int t = threadIdx.x, w = t >> 6, l = t & 63;
  int l31 = l & 31, hi = l >> 5;
  int c0 = cb * 128;
  int j0 = jB * 128 + w * 32;
  const ushort* bTb = bT + (size_t)b * 262144;
  const ushort* cTb = cT + (size_t)b * 262144;
  const ushort* dfb = dmat + (size_t)b * 2097152 + (size_t)cb * 524288;
  const float*  xb  = x;

  // cf fragments (cT unswizzled): lane n=j=l31, k chunk kc*16+hi*8
  s16x8 cf[4];
#pragma unroll
  for (int kc = 0; kc < 4; ++kc)
    cf[kc] = *reinterpret_cast<const s16x8*>(cTb + (size_t)(j0 + l31) * 64 + kc * 16 + hi * 8);

  f32x16 zero16;
#pragma unroll
  for (int r = 0; r < 16; ++r) zero16[r] = 0.f;
  f32x16 yacc[4];
#pragma unroll
  for (int ct = 0; ct < 4; ++ct) yacc[ct] = zero16;

  // stage tile it (i-range [it*64, it*64+64)) into lds2[buf]
  auto STAGE = [&](int buf, int it) {
#pragma unroll
    for (int e = 0; e < 6; ++e) {
      int q = w * 6 + e;                       // 24 chunks of 1KB
      const ushort* g;
      int loff;
      if (q < 8) { g = bTb + (size_t)it * 4096 + q * 512;       loff = q * 512; }
      else       { g = dfb + (size_t)it * 8192 + (q - 8) * 512; loff = 4096 + (q - 8) * 512; }
      gld16(g + (size_t)l * 8, &lds2[buf][loff]);
    }
  };

  STAGE(0, 0);
  asm volatile("s_waitcnt vmcnt(0)" ::: "memory");
  __syncthreads();

  int buf = 0;
  for (int it = 0; it < 64; ++it) {
    if (it < 63) STAGE(buf ^ 1, it + 1);
    __builtin_amdgcn_sched_barrier(0);
    const ushort* ldsbuf = &lds2[buf][0];
    // ---- scores (2 batches of 32 i) + exp + pack to PV B-operand
    s16x8 pf[4];
#pragma unroll
    for (int sb = 0; sb < 2; ++sb) {
      f32x16 sv = zero16;
#pragma unroll
      for (int kc = 0; kc < 4; ++kc) {
        const s16x8 bfv = *reinterpret_cast<const s16x8*>(
            ldsbuf + (32 * sb + l31) * 64 + (((2 * kc + hi) ^ (l31 & 7)) << 3));
        sv = MFMA32(bfv, cf[kc], sv);
      }
      float p[16];
#pragma unroll
      for (int r = 0; r < 16; ++r) p[r] = pexp(sv[r]);
      uint x0 = cvtpk(p[0], p[1]),   y0 = cvtpk(p[4], p[5]);
      uint x1 = cvtpk(p[2], p[3]),   y1 = cvtpk(p[6], p[7]);
      uint x2 = cvtpk(p[8], p[9]),   y2 = cvtpk(p[12], p[13]);
      uint x3 = cvtpk(p[10], p[11]), y3 = cvtpk(p[14], p[15]);
      plswap(x0, y0); plswap(x1, y1); plswap(x2, y2); plswap(x3, y3);
      u32x4 pw0 = {x0, x1, y0, y1};
      u32x4 pw1 = {x2, x3, y2, y3};
      pf[2 * sb + 0] = __builtin_bit_cast(s16x8, pw0);
      pf[2 * sb + 1] = __builtin_bit_cast(s16x8, pw1);
    }
    // ---- PV: Y[c,j] += d'[c, i-chunk ch] * P[ch][j]
#pragma unroll
    for (int ch = 0; ch < 4; ++ch) {
      const int toff = 4096 + (ch >> 1) * 4096;
      const int uoff = ((2 * (ch & 1) + hi) ^ (l31 & 3)) << 3;
#pragma unroll
      for (int ct = 0; ct < 4; ++ct) {
        const s16x8 dv = *reinterpret_cast<const s16x8*>(
            ldsbuf + toff + (32 * ct + l31) * 32 + uoff);
        yacc[ct] = MFMA32(dv, pf[ch], yacc[ct]);
      }
    }
    asm volatile("s_waitcnt vmcnt(0)" ::: "memory");
    __syncthreads();
    buf ^= 1;
  }

  // ---- epilogue: out = x + Y
#pragma unroll
  for (int ct = 0; ct < 4; ++ct) {
#pragma unroll
    for (int r = 0; r < 16; ++r) {
      int row = c0 + 32 * ct + (r & 3) + 8 * (r >> 2) + 4 * hi;
      size_t idx = ((size_t)b * 512 + row) * 4096 + j0 + l31;
      out[idx] = xb[idx] + yacc[ct][r];
    }
  }
}

extern "C" void kernel_launch(void* const* d_in, const int* in_sizes, int n_in,
                              void* d_out, int out_size, void* d_ws, size_t ws_size,
                              hipStream_t stream) {
  const float* x  = (const float*)d_in[0];
  const float* Wb = (const float*)d_in[1];
  const float* bb = (const float*)d_in[2];
  const float* Wc = (const float*)d_in[3];
  const float* bc = (const float*)d_in[4];
  const float* Wd = (const float*)d_in[5];
  const float* bd = (const float*)d_in[6];
  char* ws = (char*)d_ws;
  ushort* xT   = (ushort*)(ws + WS_XT);
  ushort* dmat = (ushort*)(ws + WS_D);
  ushort* bT   = (ushort*)(ws + WS_BT);
  ushort* cT   = (ushort*)(ws + WS_CT);
  ushort* Wcat = (ushort*)(ws + WS_WCAT);
  float*  bcat = (float*)(ws + WS_BCAT);
  float*  out  = (float*)d_out;

  k_prep_w<<<1280, 256, 0, stream>>>(Wb, bb, Wc, bc, Wd, bd, Wcat, bcat);
  k_prep_xt<<<2048, 256, 0, stream>>>(x, xT);
  k_proj<<<640, 256, 0, stream>>>(Wcat, bcat, xT, bT, cT, dmat);
  k_stats<<<256, 512, 0, stream>>>(bT, cT, dmat);
  k_attn<<<512, 256, 0, stream>>>(bT, cT, dmat, x, out);
}

// Round 7
// 243.802 us; speedup vs baseline: 2.4103x; 1.0906x over previous
//
#include <hip/hip_runtime.h>
#include <hip/hip_bf16.h>

typedef float f32x4 __attribute__((ext_vector_type(4)));
typedef float f32x16 __attribute__((ext_vector_type(16)));
typedef short s16x8 __attribute__((ext_vector_type(8)));
typedef uint  u32x4 __attribute__((ext_vector_type(4)));

#define MFMA_BF16(a, b, c) __builtin_amdgcn_mfma_f32_16x16x32_bf16((a), (b), (c), 0, 0, 0)
#define MFMA32(a, b, c)    __builtin_amdgcn_mfma_f32_32x32x16_bf16((a), (b), (c), 0, 0, 0)

// ---------- helpers ----------
__device__ __forceinline__ ushort f2bf(float f) {
  uint u = __builtin_bit_cast(uint, f);
  u += 0x7FFFu + ((u >> 16) & 1u);
  return (ushort)(u >> 16);
}
__device__ __forceinline__ uint pack2bf(float a, float b) {
  return (uint)f2bf(a) | ((uint)f2bf(b) << 16);
}
// exp(s - 30) = exp2(s*log2e - 30*log2e), raw v_exp_f32 (1 ulp)
__device__ __forceinline__ float pexp(float s) {
  float t = fmaf(s, 1.4426950408889634f, -43.2808512266689f);
  float r;
  asm("v_exp_f32 %0, %1" : "=v"(r) : "v"(t));
  return r;
}
__device__ __forceinline__ uint cvtpk(float lo, float hi) {
  uint r;
  asm("v_cvt_pk_bf16_f32 %0, %1, %2" : "=v"(r) : "v"(lo), "v"(hi));
  return r;
}
__device__ __forceinline__ void plswap(uint& a, uint& b) {
  asm("v_permlane32_swap_b32 %0, %1" : "+v"(a), "+v"(b));
}
__device__ __forceinline__ void gld16(const void* g, void* l) {
  __builtin_amdgcn_global_load_lds(
      (const __attribute__((address_space(1))) unsigned int*)g,
      (__attribute__((address_space(3))) unsigned int*)l, 16, 0, 0);
}

// ---------- ws layout (bytes) ----------
// dmat TILED: [b][cb=c>>7][it=i>>6][cl=c&127][u=((i&63)>>3)^(c&7)][i&7]  (128B rows)
// bT rows unit-swizzled: 16B unit u at row i stored at u^(i&7)
#define WS_XT    0UL
#define WS_D     16777216UL
#define WS_BT    33554432UL
#define WS_CT    35651584UL
#define WS_WCAT  37748736UL
#define WS_BCAT  38404096UL

// ---------- kernel 1: pack weights to bf16 [640][512] + bias concat ----------
__global__ void k_prep_w(const float* __restrict__ Wb, const float* __restrict__ bb,
                         const float* __restrict__ Wc, const float* __restrict__ bc,
                         const float* __restrict__ Wd, const float* __restrict__ bd,
                         ushort* __restrict__ Wcat, float* __restrict__ bcat) {
  int idx = blockIdx.x * 256 + threadIdx.x;
  if (idx < 640 * 512) {
    int m = idx >> 9, k = idx & 511;
    float v = (m < 64) ? Wb[m * 512 + k] : (m < 128) ? Wc[(m - 64) * 512 + k] : Wd[(m - 128) * 512 + k];
    Wcat[idx] = f2bf(v);
  }
  if (idx < 640) {
    bcat[idx] = (idx < 64) ? bb[idx] : (idx < 128) ? bc[idx - 64] : bd[idx - 128];
  }
}

// ---------- kernel 2: transpose x [B][512][4096] f32 -> xT [B][4096][512] bf16 ----------
__global__ __launch_bounds__(256) void k_prep_xt(const float* __restrict__ x, ushort* __restrict__ xT) {
  __shared__ float tile[64][65];
  int bx = blockIdx.x;
  int b = bx >> 9;                  // 8*64 = 512 tiles per batch
  int c0 = ((bx >> 6) & 7) * 64;
  int n0 = (bx & 63) * 64;
  int t = threadIdx.x;
  const float* xb = x + (size_t)b * 512 * 4096;
#pragma unroll
  for (int p = 0; p < 4; ++p) {
    int cl = (t >> 4) + 16 * p;
    int nf = (t & 15) * 4;
    float4 v = *reinterpret_cast<const float4*>(xb + (size_t)(c0 + cl) * 4096 + n0 + nf);
    tile[cl][nf + 0] = v.x; tile[cl][nf + 1] = v.y; tile[cl][nf + 2] = v.z; tile[cl][nf + 3] = v.w;
  }
  __syncthreads();
  ushort* dst = xT + (size_t)b * 4096 * 512;
#pragma unroll
  for (int q = 0; q < 2; ++q) {
    int ch = t + 256 * q;
    int nl = ch >> 3;
    int cf = (ch & 7) * 8;
    uint4 o;
    o.x = pack2bf(tile[cf + 0][nl], tile[cf + 1][nl]);
    o.y = pack2bf(tile[cf + 2][nl], tile[cf + 3][nl]);
    o.z = pack2bf(tile[cf + 4][nl], tile[cf + 5][nl]);
    o.w = pack2bf(tile[cf + 6][nl], tile[cf + 7][nl]);
    *reinterpret_cast<uint4*>(dst + (size_t)(n0 + nl) * 512 + c0 + cf) = o;
  }
}

// ---------- kernel 3: projection GEMM [640 x 4096, K=512] per batch ----------
__global__ __launch_bounds__(256) void k_proj(const ushort* __restrict__ Wcat, const float* __restrict__ bcat,
                                              const ushort* __restrict__ xT, ushort* __restrict__ bT,
                                              ushort* __restrict__ cT, ushort* __restrict__ dmat) {
  int bx = blockIdx.x;
  int b = bx / 160;
  int r = bx % 160;
  int m0 = (r >> 5) * 128;    // 5 m-tiles
  int n0 = (r & 31) * 128;    // 32 n-tiles
  int t = threadIdx.x, l = t & 63, w = t >> 6;
  int wm = w >> 1, wn = w & 1, g = l >> 4, l15 = l & 15;
  const ushort* xb = xT + (size_t)b * 4096 * 512;
  f32x4 acc[4][4] = {};
  s16x8 bfn[4];
#pragma unroll
  for (int nt = 0; nt < 4; ++nt)
    bfn[nt] = *reinterpret_cast<const s16x8*>(xb + (size_t)(n0 + 64 * wn + 16 * nt + l15) * 512 + 8 * g);
  for (int k0 = 0; k0 < 512; k0 += 32) {
    s16x8 a[4], bf[4];
#pragma unroll
    for (int nt = 0; nt < 4; ++nt) bf[nt] = bfn[nt];
#pragma unroll
    for (int mt = 0; mt < 4; ++mt)
      a[mt] = *reinterpret_cast<const s16x8*>(Wcat + (size_t)(m0 + 64 * wm + 16 * mt + l15) * 512 + k0 + 8 * g);
    if (k0 + 32 < 512) {
#pragma unroll
      for (int nt = 0; nt < 4; ++nt)
        bfn[nt] = *reinterpret_cast<const s16x8*>(xb + (size_t)(n0 + 64 * wn + 16 * nt + l15) * 512 + k0 + 32 + 8 * g);
    }
    __builtin_amdgcn_sched_barrier(0);
#pragma unroll
    for (int mt = 0; mt < 4; ++mt)
#pragma unroll
      for (int nt = 0; nt < 4; ++nt)
        acc[mt][nt] = MFMA_BF16(a[mt], bf[nt], acc[mt][nt]);
  }
#pragma unroll
  for (int mt = 0; mt < 4; ++mt) {
    int mbase = m0 + 64 * wm + 16 * mt + 4 * g;
#pragma unroll
    for (int nt = 0; nt < 4; ++nt) {
      int n = n0 + 64 * wn + 16 * nt + l15;
      float vv[4];
      vv[0] = acc[mt][nt][0] + bcat[mbase + 0];
      vv[1] = acc[mt][nt][1] + bcat[mbase + 1];
      vv[2] = acc[mt][nt][2] + bcat[mbase + 2];
      vv[3] = acc[mt][nt][3] + bcat[mbase + 3];
      if (mbase < 64) {
        // bT swizzled: unit u=mbase>>3 stored at u^(n&7); mbase&4 selects 8B half
        uint2 u2; u2.x = pack2bf(vv[0], vv[1]); u2.y = pack2bf(vv[2], vv[3]);
        size_t off = ((size_t)b * 4096 + n) * 64 + (size_t)((((mbase >> 3) ^ (n & 7)) << 3) + (mbase & 4));
        *reinterpret_cast<uint2*>(bT + off) = u2;
      } else if (mbase < 128) {
        uint2 u2; u2.x = pack2bf(vv[0], vv[1]); u2.y = pack2bf(vv[2], vv[3]);
        *reinterpret_cast<uint2*>(cT + ((size_t)b * 4096 + n) * 64 + (mbase - 64)) = u2;
      } else {
        // d tiled+swizzled: [b][c>>7][n>>6][c&127][((n&63)>>3)^(c&7)][n&7]
        int cc = mbase - 128;            // multiple of 4
        size_t base = (size_t)b * 2097152 + (size_t)(cc >> 7) * 524288 + (size_t)(n >> 6) * 8192;
#pragma unroll
        for (int rr = 0; rr < 4; ++rr) {
          int c = cc + rr;
          dmat[base + (size_t)(c & 127) * 64 + ((((n >> 3) & 7) ^ (c & 7)) << 3) + (n & 7)] = f2bf(vv[rr]);
        }
      }
    }
  }
}

// ---------- kernel 4: stats + fold  d[c,i] *= 1/sum_j exp(s_ij - 30) ----------
__global__ __launch_bounds__(512) void k_stats(const ushort* __restrict__ bT, const ushort* __restrict__ cT,
                                               ushort* __restrict__ dmat) {
  __shared__ float lsum[64];
  int bx = blockIdx.x;
  int b = bx >> 6;
  int i0 = (bx & 63) * 64;
  int t = threadIdx.x, l = t & 63, w = t >> 6;
  int wm = w >> 1, wn = w & 1, g = l >> 4, l15 = l & 15;
  if (t < 64) lsum[t] = 0.f;
  __syncthreads();
  const ushort* bTb = bT + (size_t)b * 4096 * 64;
  const ushort* cTb = cT + (size_t)b * 4096 * 64;
  int arow = i0 + 16 * wm + l15;
  int r7 = arow & 7;
  const ushort* abase = bTb + (size_t)arow * 64;
  s16x8 a0 = *reinterpret_cast<const s16x8*>(abase + ((g ^ r7) << 3));
  s16x8 a1 = *reinterpret_cast<const s16x8*>(abase + (((g + 4) ^ r7) << 3));
  float lacc[4] = {0.f, 0.f, 0.f, 0.f};
  s16x8 b0n[4], b1n[4];
#pragma unroll
  for (int nt = 0; nt < 4; ++nt) {
    const ushort* cr = cTb + (size_t)(64 * wn + 16 * nt + l15) * 64 + 8 * g;
    b0n[nt] = *reinterpret_cast<const s16x8*>(cr);
    b1n[nt] = *reinterpret_cast<const s16x8*>(cr + 32);
  }
  for (int it = 0; it < 32; ++it) {
    s16x8 b0[4], b1[4];
#pragma unroll
    for (int nt = 0; nt < 4; ++nt) { b0[nt] = b0n[nt]; b1[nt] = b1n[nt]; }
    if (it + 1 < 32) {
      int jb = 64 * wn + 128 * (it + 1);
#pragma unroll
      for (int nt = 0; nt < 4; ++nt) {
        const ushort* cr = cTb + (size_t)(jb + 16 * nt + l15) * 64 + 8 * g;
        b0n[nt] = *reinterpret_cast<const s16x8*>(cr);
        b1n[nt] = *reinterpret_cast<const s16x8*>(cr + 32);
      }
    }
    __builtin_amdgcn_sched_barrier(0);
#pragma unroll
    for (int nt = 0; nt < 4; ++nt) {
      f32x4 s = {0.f, 0.f, 0.f, 0.f};
      s = MFMA_BF16(a0, b0[nt], s);
      s = MFMA_BF16(a1, b1[nt], s);
#pragma unroll
      for (int rr = 0; rr < 4; ++rr) lacc[rr] += pexp(s[rr]);
    }
  }
#pragma unroll
  for (int off = 1; off < 16; off <<= 1)
#pragma unroll
    for (int rr = 0; rr < 4; ++rr) lacc[rr] += __shfl_xor(lacc[rr], off);
  if (l15 == 0) {
#pragma unroll
    for (int rr = 0; rr < 4; ++rr) atomicAdd(&lsum[16 * wm + 4 * g + rr], lacc[rr]);
  }
  __syncthreads();
  if (t < 64) lsum[t] = 1.0f / fmaxf(lsum[t], 1e-30f);
  __syncthreads();
  // rescale dmat row c=t, cols [i0, i0+64) in the tiled+swizzled layout
  ushort* dbase = dmat + (size_t)b * 2097152 + (size_t)(t >> 7) * 524288 +
                  (size_t)(i0 >> 6) * 8192 + (size_t)(t & 127) * 64;
  int c7 = t & 7;
#pragma unroll
  for (int q = 0; q < 8; ++q) {
    size_t off = (size_t)((q ^ c7) << 3);
    s16x8 v = *reinterpret_cast<s16x8*>(dbase + off);
    s16x8 nv;
#pragma unroll
    for (int e = 0; e < 8; ++e) {
      float f = __builtin_bit_cast(float, ((uint)(ushort)v[e]) << 16) * lsum[q * 8 + e];
      nv[e] = (short)f2bf(f);
    }
    *reinterpret_cast<s16x8*>(dbase + off) = nv;
  }
}

// ---------- kernel 5: fused  Y = d' . exp(S-30) ; out = x + Y ----------
// Block = 4 waves, tile (b, 128 c, 128 j); wave w owns j-sub of 32. i-step 64.
// 3-buffer LDS pipeline (bT 8KB + d 16KB per tile), STAGE issued 2 tiles ahead,
// counted s_waitcnt vmcnt(6) + raw s_barrier (loads stay in flight across
// barriers). Both LDS reads conflict-free via source-side XOR swizzles.
__global__ __launch_bounds__(256, 2) void k_attn(const ushort* __restrict__ bT, const ushort* __restrict__ cT,
                                                 const ushort* __restrict__ dmat,
                                                 const float* __restrict__ x, float* __restrict__ out) {
  __shared__ ushort lds3[3][12288];           // [buf][ bf 8KB=4096u | df 16KB=8192u ]
  int bid = blockIdx.x;                       // 512 blocks, 2/CU
  int swz = (bid & 7) * 64 + (bid >> 3);      // XCD grouping: 64 consecutive jobs/XCD
  int b  = swz >> 7;
  int cb = (swz >> 5) & 3;
  int jB = swz & 31;
  int t = threadIdx.x, w = t >> 6, l = t & 63;
  int l31 = l & 31, hi = l >> 5;
  int c0 = cb * 128;
  int j0 = jB * 128 + w * 32;
  const ushort* bTb = bT + (size_t)b * 262144;
  const ushort* cTb = cT + (size_t)b * 262144;
  const ushort* dfb = dmat + (size_t)b * 2097152 + (size_t)cb * 524288;

  // cf fragments (cT unswizzled): lane n=j=l31, k chunk kc*16+hi*8
  s16x8 cf[4];
#pragma unroll
  for (int kc = 0; kc < 4; ++kc)
    cf[kc] = *reinterpret_cast<const s16x8*>(cTb + (size_t)(j0 + l31) * 64 + kc * 16 + hi * 8);

  f32x16 zero16;
#pragma unroll
  for (int r = 0; r < 16; ++r) zero16[r] = 0.f;
  f32x16 yacc[4];
#pragma unroll
  for (int ct = 0; ct < 4; ++ct) yacc[ct] = zero16;

  // stage tile it (i-range [it*64, it*64+64)) into lds3[buf]: 24 x 1KB chunks
  auto STAGE = [&](int buf, int it) {
#pragma unroll
    for (int e = 0; e < 6; ++e) {
      int q = w * 6 + e;
      const ushort* g;
      int loff;
      if (q < 8) { g = bTb + (size_t)it * 4096 + q * 512;       loff = q * 512; }
      else       { g = dfb + (size_t)it * 8192 + (q - 8) * 512; loff = 4096 + (q - 8) * 512; }
      gld16(g + (size_t)l * 8, &lds3[buf][loff]);
    }
  };

  STAGE(0, 0);
  STAGE(1, 1);
  asm volatile("s_waitcnt vmcnt(6)" ::: "memory");   // tile 0 landed
  __builtin_amdgcn_s_barrier();
  __builtin_amdgcn_sched_barrier(0);

  for (int it = 0; it < 64; ++it) {
    if (it + 2 < 64) STAGE((it + 2) % 3, it + 2);
    __builtin_amdgcn_sched_barrier(0);
    const ushort* ldsbuf = &lds3[it % 3][0];
    // ---- scores (2 batches of 32 i) + exp + pack to PV B-operand
    s16x8 pf[4];
#pragma unroll
    for (int sb = 0; sb < 2; ++sb) {
      f32x16 sv = zero16;
      __builtin_amdgcn_s_setprio(1);
#pragma unroll
      for (int kc = 0; kc < 4; ++kc) {
        const s16x8 bfv = *reinterpret_cast<const s16x8*>(
            ldsbuf + (32 * sb + l31) * 64 + (((2 * kc + hi) ^ (l31 & 7)) << 3));
        sv = MFMA32(bfv, cf[kc], sv);
      }
      __builtin_amdgcn_s_setprio(0);
      float p[16];
#pragma unroll
      for (int r = 0; r < 16; ++r) p[r] = pexp(sv[r]);
      uint x0 = cvtpk(p[0], p[1]),   y0 = cvtpk(p[4], p[5]);
      uint x1 = cvtpk(p[2], p[3]),   y1 = cvtpk(p[6], p[7]);
      uint x2 = cvtpk(p[8], p[9]),   y2 = cvtpk(p[12], p[13]);
      uint x3 = cvtpk(p[10], p[11]), y3 = cvtpk(p[14], p[15]);
      plswap(x0, y0); plswap(x1, y1); plswap(x2, y2); plswap(x3, y3);
      u32x4 pw0 = {x0, x1, y0, y1};
      u32x4 pw1 = {x2, x3, y2, y3};
      pf[2 * sb + 0] = __builtin_bit_cast(s16x8, pw0);
      pf[2 * sb + 1] = __builtin_bit_cast(s16x8, pw1);
    }
    // ---- PV: Y[c,j] += d'[c, i-chunk ch] * P[ch][j]  (d rows 128B, XOR c&7)
    __builtin_amdgcn_s_setprio(1);
#pragma unroll
    for (int ch = 0; ch < 4; ++ch) {
      const int uoff = ((2 * ch + hi) ^ (l31 & 7)) << 3;
#pragma unroll
      for (int ct = 0; ct < 4; ++ct) {
        const s16x8 dv = *reinterpret_cast<const s16x8*>(
            ldsbuf + 4096 + (32 * ct + l31) * 64 + uoff);
        yacc[ct] = MFMA32(dv, pf[ch], yacc[ct]);
      }
    }
    __builtin_amdgcn_s_setprio(0);
    __builtin_amdgcn_sched_barrier(0);
    // counted wait: tile it+1 (issued 1 iter ago) complete; tile it+2 (6 loads)
    // may remain in flight. Tail iterations drain fully.
    if (it < 62) { asm volatile("s_waitcnt vmcnt(6)" ::: "memory"); }
    else         { asm volatile("s_waitcnt vmcnt(0)" ::: "memory"); }
    __builtin_amdgcn_s_barrier();
    __builtin_amdgcn_sched_barrier(0);
  }

  // ---- epilogue: out = x + Y
#pragma unroll
  for (int ct = 0; ct < 4; ++ct) {
#pragma unroll
    for (int r = 0; r < 16; ++r) {
      int row = c0 + 32 * ct + (r & 3) + 8 * (r >> 2) + 4 * hi;
      size_t idx = ((size_t)b * 512 + row) * 4096 + j0 + l31;
      out[idx] = x[idx] + yacc[ct][r];
    }
  }
}

extern "C" void kernel_launch(void* const* d_in, const int* in_sizes, int n_in,
                              void* d_out, int out_size, void* d_ws, size_t ws_size,
                              hipStream_t stream) {
  const float* x  = (const float*)d_in[0];
  const float* Wb = (const float*)d_in[1];
  const float* bb = (const float*)d_in[2];
  const float* Wc = (const float*)d_in[3];
  const float* bc = (const float*)d_in[4];
  const float* Wd = (const float*)d_in[5];
  const float* bd = (const float*)d_in[6];
  char* ws = (char*)d_ws;
  ushort* xT   = (ushort*)(ws + WS_XT);
  ushort* dmat = (ushort*)(ws + WS_D);
  ushort* bT   = (ushort*)(ws + WS_BT);
  ushort* cT   = (ushort*)(ws + WS_CT);
  ushort* Wcat = (ushort*)(ws + WS_WCAT);
  float*  bcat = (float*)(ws + WS_BCAT);
  float*  out  = (float*)d_out;

  k_prep_w<<<1280, 256, 0, stream>>>(Wb, bb, Wc, bc, Wd, bd, Wcat, bcat);
  k_prep_xt<<<2048, 256, 0, stream>>>(x, xT);
  k_proj<<<640, 256, 0, stream>>>(Wcat, bcat, xT, bT, cT, dmat);
  k_stats<<<256, 512, 0, stream>>>(bT, cT, dmat);
  k_attn<<<512, 256, 0, stream>>>(bT, cT, dmat, x, out);
}

// Round 8
// 234.424 us; speedup vs baseline: 2.5067x; 1.0400x over previous
//
#include <hip/hip_runtime.h>
#include <hip/hip_bf16.h>

typedef float f32x4 __attribute__((ext_vector_type(4)));
typedef float f32x16 __attribute__((ext_vector_type(16)));
typedef short s16x8 __attribute__((ext_vector_type(8)));
typedef uint  u32x4 __attribute__((ext_vector_type(4)));

#define MFMA_BF16(a, b, c) __builtin_amdgcn_mfma_f32_16x16x32_bf16((a), (b), (c), 0, 0, 0)
#define MFMA32(a, b, c)    __builtin_amdgcn_mfma_f32_32x32x16_bf16((a), (b), (c), 0, 0, 0)

// ---------- helpers ----------
__device__ __forceinline__ ushort f2bf(float f) {
  uint u = __builtin_bit_cast(uint, f);
  u += 0x7FFFu + ((u >> 16) & 1u);
  return (ushort)(u >> 16);
}
__device__ __forceinline__ uint pack2bf(float a, float b) {
  return (uint)f2bf(a) | ((uint)f2bf(b) << 16);
}
// exp(s - 30) = exp2(fma(s, log2e, -30*log2e))
__device__ __forceinline__ float pexp(float s) {
  float t = fmaf(s, 1.4426950408889634f, -43.2808512266689f);
  float r;
  asm("v_exp_f32 %0, %1" : "=v"(r) : "v"(t));
  return r;
}
__device__ __forceinline__ uint cvtpk(float lo, float hi) {
  uint r;
  asm("v_cvt_pk_bf16_f32 %0, %1, %2" : "=v"(r) : "v"(lo), "v"(hi));
  return r;
}
__device__ __forceinline__ void plswap(uint& a, uint& b) {
  asm("v_permlane32_swap_b32 %0, %1" : "+v"(a), "+v"(b));
}
__device__ __forceinline__ void gld16(const void* g, void* l) {
  __builtin_amdgcn_global_load_lds(
      (const __attribute__((address_space(1))) unsigned int*)g,
      (__attribute__((address_space(3))) unsigned int*)l, 16, 0, 0);
}

// ---------- ws layout (bytes) ----------
// dmat FRAGMENT-MAJOR: elem (b,c,i) at ((((b*256 + (i>>4))*16 + (c>>5))*64
//                                        + ((i>>3)&1)*32 + (c&31))*8 + (i&7)
// bT rows unit-swizzled: 16B unit u at row i stored at u^(i&7)
#define WS_XT    0UL
#define WS_D     16777216UL
#define WS_BT    33554432UL
#define WS_CT    35651584UL
#define WS_WCAT  37748736UL
#define WS_BCAT  38404096UL

// ---------- kernel 1: pack weights to bf16 [640][512] + bias concat ----------
__global__ void k_prep_w(const float* __restrict__ Wb, const float* __restrict__ bb,
                         const float* __restrict__ Wc, const float* __restrict__ bc,
                         const float* __restrict__ Wd, const float* __restrict__ bd,
                         ushort* __restrict__ Wcat, float* __restrict__ bcat) {
  int idx = blockIdx.x * 256 + threadIdx.x;
  if (idx < 640 * 512) {
    int m = idx >> 9, k = idx & 511;
    float v = (m < 64) ? Wb[m * 512 + k] : (m < 128) ? Wc[(m - 64) * 512 + k] : Wd[(m - 128) * 512 + k];
    Wcat[idx] = f2bf(v);
  }
  if (idx < 640) {
    bcat[idx] = (idx < 64) ? bb[idx] : (idx < 128) ? bc[idx - 64] : bd[idx - 128];
  }
}

// ---------- kernel 2: transpose x [B][512][4096] f32 -> xT [B][4096][512] bf16 ----------
__global__ __launch_bounds__(256) void k_prep_xt(const float* __restrict__ x, ushort* __restrict__ xT) {
  __shared__ float tile[64][65];
  int bx = blockIdx.x;
  int b = bx >> 9;                  // 8*64 = 512 tiles per batch
  int c0 = ((bx >> 6) & 7) * 64;
  int n0 = (bx & 63) * 64;
  int t = threadIdx.x;
  const float* xb = x + (size_t)b * 512 * 4096;
#pragma unroll
  for (int p = 0; p < 4; ++p) {
    int cl = (t >> 4) + 16 * p;
    int nf = (t & 15) * 4;
    float4 v = *reinterpret_cast<const float4*>(xb + (size_t)(c0 + cl) * 4096 + n0 + nf);
    tile[cl][nf + 0] = v.x; tile[cl][nf + 1] = v.y; tile[cl][nf + 2] = v.z; tile[cl][nf + 3] = v.w;
  }
  __syncthreads();
  ushort* dst = xT + (size_t)b * 4096 * 512;
#pragma unroll
  for (int q = 0; q < 2; ++q) {
    int ch = t + 256 * q;
    int nl = ch >> 3;
    int cf = (ch & 7) * 8;
    uint4 o;
    o.x = pack2bf(tile[cf + 0][nl], tile[cf + 1][nl]);
    o.y = pack2bf(tile[cf + 2][nl], tile[cf + 3][nl]);
    o.z = pack2bf(tile[cf + 4][nl], tile[cf + 5][nl]);
    o.w = pack2bf(tile[cf + 6][nl], tile[cf + 7][nl]);
    *reinterpret_cast<uint4*>(dst + (size_t)(n0 + nl) * 512 + c0 + cf) = o;
  }
}

// ---------- kernel 3: projection GEMM [640 x 4096, K=512] per batch ----------
__global__ __launch_bounds__(256) void k_proj(const ushort* __restrict__ Wcat, const float* __restrict__ bcat,
                                              const ushort* __restrict__ xT, ushort* __restrict__ bT,
                                              ushort* __restrict__ cT, ushort* __restrict__ dmat) {
  int bx = blockIdx.x;
  int b = bx / 160;
  int r = bx % 160;
  int m0 = (r >> 5) * 128;    // 5 m-tiles
  int n0 = (r & 31) * 128;    // 32 n-tiles
  int t = threadIdx.x, l = t & 63, w = t >> 6;
  int wm = w >> 1, wn = w & 1, g = l >> 4, l15 = l & 15;
  const ushort* xb = xT + (size_t)b * 4096 * 512;
  f32x4 acc[4][4] = {};
  s16x8 bfn[4];
#pragma unroll
  for (int nt = 0; nt < 4; ++nt)
    bfn[nt] = *reinterpret_cast<const s16x8*>(xb + (size_t)(n0 + 64 * wn + 16 * nt + l15) * 512 + 8 * g);
  for (int k0 = 0; k0 < 512; k0 += 32) {
    s16x8 a[4], bf[4];
#pragma unroll
    for (int nt = 0; nt < 4; ++nt) bf[nt] = bfn[nt];
#pragma unroll
    for (int mt = 0; mt < 4; ++mt)
      a[mt] = *reinterpret_cast<const s16x8*>(Wcat + (size_t)(m0 + 64 * wm + 16 * mt + l15) * 512 + k0 + 8 * g);
    if (k0 + 32 < 512) {
#pragma unroll
      for (int nt = 0; nt < 4; ++nt)
        bfn[nt] = *reinterpret_cast<const s16x8*>(xb + (size_t)(n0 + 64 * wn + 16 * nt + l15) * 512 + k0 + 32 + 8 * g);
    }
    __builtin_amdgcn_sched_barrier(0);
#pragma unroll
    for (int mt = 0; mt < 4; ++mt)
#pragma unroll
      for (int nt = 0; nt < 4; ++nt)
        acc[mt][nt] = MFMA_BF16(a[mt], bf[nt], acc[mt][nt]);
  }
#pragma unroll
  for (int mt = 0; mt < 4; ++mt) {
    int mbase = m0 + 64 * wm + 16 * mt + 4 * g;
#pragma unroll
    for (int nt = 0; nt < 4; ++nt) {
      int n = n0 + 64 * wn + 16 * nt + l15;
      float vv[4];
      vv[0] = acc[mt][nt][0] + bcat[mbase + 0];
      vv[1] = acc[mt][nt][1] + bcat[mbase + 1];
      vv[2] = acc[mt][nt][2] + bcat[mbase + 2];
      vv[3] = acc[mt][nt][3] + bcat[mbase + 3];
      if (mbase < 64) {
        // bT swizzled: unit u=mbase>>3 stored at u^(n&7); mbase&4 selects 8B half
        uint2 u2; u2.x = pack2bf(vv[0], vv[1]); u2.y = pack2bf(vv[2], vv[3]);
        size_t off = ((size_t)b * 4096 + n) * 64 + (size_t)((((mbase >> 3) ^ (n & 7)) << 3) + (mbase & 4));
        *reinterpret_cast<uint2*>(bT + off) = u2;
      } else if (mbase < 128) {
        uint2 u2; u2.x = pack2bf(vv[0], vv[1]); u2.y = pack2bf(vv[2], vv[3]);
        *reinterpret_cast<uint2*>(cT + ((size_t)b * 4096 + n) * 64 + (mbase - 64)) = u2;
      } else {
        // d fragment-major: (b, c, i=n)
        int cc = mbase - 128;
        size_t fb = (((size_t)b * 256 + (n >> 4)) * 16) * 512;  // *64 lanes *8 elems
#pragma unroll
        for (int rr = 0; rr < 4; ++rr) {
          int c = cc + rr;
          size_t idx = fb + (size_t)(c >> 5) * 512 + (size_t)(((n >> 3) & 1) * 32 + (c & 31)) * 8 + (n & 7);
          dmat[idx] = f2bf(vv[rr]);
        }
      }
    }
  }
}

// ---------- kernel 4: stats + fold  d[c,i] *= 1/sum_j exp(s_ij - 30) ----------
__global__ __launch_bounds__(512) void k_stats(const ushort* __restrict__ bT, const ushort* __restrict__ cT,
                                               ushort* __restrict__ dmat) {
  __shared__ float lsum[64];
  int bx = blockIdx.x;
  int b = bx >> 6;
  int i0 = (bx & 63) * 64;
  int t = threadIdx.x, l = t & 63, w = t >> 6;
  int wm = w >> 1, wn = w & 1, g = l >> 4, l15 = l & 15;
  if (t < 64) lsum[t] = 0.f;
  __syncthreads();
  const ushort* bTb = bT + (size_t)b * 4096 * 64;
  const ushort* cTb = cT + (size_t)b * 4096 * 64;
  int arow = i0 + 16 * wm + l15;
  int r7 = arow & 7;
  const ushort* abase = bTb + (size_t)arow * 64;
  s16x8 a0 = *reinterpret_cast<const s16x8*>(abase + ((g ^ r7) << 3));
  s16x8 a1 = *reinterpret_cast<const s16x8*>(abase + (((g + 4) ^ r7) << 3));
  float lacc[4] = {0.f, 0.f, 0.f, 0.f};
  s16x8 b0n[4], b1n[4];
#pragma unroll
  for (int nt = 0; nt < 4; ++nt) {
    const ushort* cr = cTb + (size_t)(64 * wn + 16 * nt + l15) * 64 + 8 * g;
    b0n[nt] = *reinterpret_cast<const s16x8*>(cr);
    b1n[nt] = *reinterpret_cast<const s16x8*>(cr + 32);
  }
  for (int it = 0; it < 32; ++it) {
    s16x8 b0[4], b1[4];
#pragma unroll
    for (int nt = 0; nt < 4; ++nt) { b0[nt] = b0n[nt]; b1[nt] = b1n[nt]; }
    if (it + 1 < 32) {
      int jb = 64 * wn + 128 * (it + 1);
#pragma unroll
      for (int nt = 0; nt < 4; ++nt) {
        const ushort* cr = cTb + (size_t)(jb + 16 * nt + l15) * 64 + 8 * g;
        b0n[nt] = *reinterpret_cast<const s16x8*>(cr);
        b1n[nt] = *reinterpret_cast<const s16x8*>(cr + 32);
      }
    }
    __builtin_amdgcn_sched_barrier(0);
#pragma unroll
    for (int nt = 0; nt < 4; ++nt) {
      f32x4 s = {0.f, 0.f, 0.f, 0.f};
      s = MFMA_BF16(a0, b0[nt], s);
      s = MFMA_BF16(a1, b1[nt], s);
#pragma unroll
      for (int rr = 0; rr < 4; ++rr) lacc[rr] += pexp(s[rr]);
    }
  }
#pragma unroll
  for (int off = 1; off < 16; off <<= 1)
#pragma unroll
    for (int rr = 0; rr < 4; ++rr) lacc[rr] += __shfl_xor(lacc[rr], off);
  if (l15 == 0) {
#pragma unroll
    for (int rr = 0; rr < 4; ++rr) atomicAdd(&lsum[16 * wm + 4 * g + rr], lacc[rr]);
  }
  __syncthreads();
  if (t < 64) lsum[t] = 1.0f / fmaxf(lsum[t], 1e-30f);
  __syncthreads();
  // rescale d row c=t, cols [i0, i0+64) in the fragment-major layout
  int c = t;
  size_t rowb = (size_t)(c >> 5) * 512 + (size_t)(c & 31) * 8;
#pragma unroll
  for (int q = 0; q < 8; ++q) {
    int ic = (i0 >> 4) + (q >> 1);
    size_t idx = (((size_t)b * 256 + ic) * 16) * 512 + rowb + (size_t)(q & 1) * 256;
    s16x8 v = *reinterpret_cast<s16x8*>(dmat + idx);
    s16x8 nv;
#pragma unroll
    for (int e = 0; e < 8; ++e) {
      float f = __builtin_bit_cast(float, ((uint)(ushort)v[e]) << 16) * lsum[q * 8 + e];
      nv[e] = (short)f2bf(f);
    }
    *reinterpret_cast<s16x8*>(dmat + idx) = nv;
  }
}

// ---------- kernel 5: fused  Y = d' . exp(S-30) ; out = x + Y ----------
// Block = (b, cb2, jB): 256 c x 128 j, 8 waves (512 thr), i-step 64.
// Scores computed ONCE per block (wave w -> S-tile (w>>2, w&3)), shared via
// double-buffered LDS P (one barrier/iter). d read DIRECT global->reg from
// fragment-major dmat (coalesced 1KB/instr, no LDS). bT gld_lds tri-buffer
// with counted vmcnt(1). 2x total score redundancy (was 4x).
__global__ __launch_bounds__(512, 2) void k_attn(const ushort* __restrict__ bT, const ushort* __restrict__ cT,
                                                 const ushort* __restrict__ dmat,
                                                 const float* __restrict__ x, float* __restrict__ out) {
  __shared__ ushort sBT[3][4096];   // 3 x 8KB bT tiles (64 i x 128B swizzled rows)
  __shared__ ushort sP[2][8192];    // 2 x 16KB P: [16 frags][64 lanes][8 bf16]
  int bid = blockIdx.x;             // 256 blocks
  int gid = (bid & 7) * 32 + (bid >> 3);   // XCD-grouped, bijective
  int b   = gid >> 6;
  int cb2 = (gid >> 5) & 1;
  int jB  = gid & 31;
  int t = threadIdx.x, w = t >> 6, l = t & 63;
  int l31 = l & 31, hi = l >> 5;
  int it_s = w >> 2, jt_s = w & 3;  // scoring role: S-tile (32i x 32j)
  int cg = w >> 1, jg = w & 1;      // PV role: 64c x 64j
  const ushort* bTb = bT + (size_t)b * 262144;
  const ushort* cTb = cT + (size_t)b * 262144;

  // cf: B-operand of scores, fixed (this wave's scoring 32 j)
  int js = jB * 128 + jt_s * 32 + l31;
  s16x8 cf[4];
#pragma unroll
  for (int kc = 0; kc < 4; ++kc)
    cf[kc] = *reinterpret_cast<const s16x8*>(cTb + (size_t)js * 64 + kc * 16 + hi * 8);

  int ctg0 = cb2 * 8 + cg * 2;      // PV c-tile pair (absolute /32 index)
  f32x16 zero16;
#pragma unroll
  for (int r = 0; r < 16; ++r) zero16[r] = 0.f;
  f32x16 yacc[2][2];                // [k=ct][jj=jt]
  yacc[0][0] = zero16; yacc[0][1] = zero16; yacc[1][0] = zero16; yacc[1][1] = zero16;

  // STAGE: one gld16 per thread per tile (8KB)
  auto STAGE = [&](int it) {
    gld16(bTb + (size_t)it * 4096 + (size_t)t * 8, &sBT[it % 3][t * 8]);
  };

  STAGE(0); STAGE(1);
  asm volatile("s_waitcnt vmcnt(1)" ::: "memory");   // tile 0 landed
  __builtin_amdgcn_s_barrier();
  __builtin_amdgcn_sched_barrier(0);

  for (int it = 0; it < 64; ++it) {
    // [a] d fragments for this iter: direct global, coalesced 1KB each
    s16x8 dv[2][4];
#pragma unroll
    for (int ch = 0; ch < 4; ++ch) {
#pragma unroll
      for (int k = 0; k < 2; ++k)
        dv[k][ch] = *reinterpret_cast<const s16x8*>(
            dmat + ((((size_t)b * 256 + (4 * it + ch)) * 16 + (ctg0 + k)) * 64 + l) * 8);
    }
    // [b] stage bT tile it+2
    if (it + 2 < 64) STAGE(it + 2);
    __builtin_amdgcn_sched_barrier(0);
    // [c] scores: one 32x32 S-tile per wave, K=64
    const ushort* bbuf = &sBT[it % 3][0];
    f32x16 sv = zero16;
    __builtin_amdgcn_s_setprio(1);
#pragma unroll
    for (int kc = 0; kc < 4; ++kc) {
      const s16x8 bfv = *reinterpret_cast<const s16x8*>(
          bbuf + (32 * it_s + l31) * 64 + (((2 * kc + hi) ^ (l31 & 7)) << 3));
      sv = MFMA32(bfv, cf[kc], sv);
    }
    __builtin_amdgcn_s_setprio(0);
    float p[16];
#pragma unroll
    for (int r = 0; r < 16; ++r) p[r] = pexp(sv[r]);
    uint x0 = cvtpk(p[0], p[1]),   y0 = cvtpk(p[4], p[5]);
    uint x1 = cvtpk(p[2], p[3]),   y1 = cvtpk(p[6], p[7]);
    uint x2 = cvtpk(p[8], p[9]),   y2 = cvtpk(p[12], p[13]);
    uint x3 = cvtpk(p[10], p[11]), y3 = cvtpk(p[14], p[15]);
    plswap(x0, y0); plswap(x1, y1); plswap(x2, y2); plswap(x3, y3);
    u32x4 pw0 = {x0, x1, y0, y1};
    u32x4 pw1 = {x2, x3, y2, y3};
    ushort* pbuf = &sP[it & 1][0];
    int fi0 = jt_s * 4 + 2 * it_s;
    *reinterpret_cast<s16x8*>(pbuf + (fi0 * 64 + l) * 8)       = __builtin_bit_cast(s16x8, pw0);
    *reinterpret_cast<s16x8*>(pbuf + ((fi0 + 1) * 64 + l) * 8) = __builtin_bit_cast(s16x8, pw1);
    // barrier: P writes visible; prev readers of this P buffer done (skew<=1 iter)
    asm volatile("s_waitcnt lgkmcnt(0)" ::: "memory");
    __builtin_amdgcn_s_barrier();
    // [e] counted wait: drain d(it) (+stage it+1); keep stage(it+2) in flight
    if (it < 62) { asm volatile("s_waitcnt vmcnt(1)" ::: "memory"); }
    else         { asm volatile("s_waitcnt vmcnt(0)" ::: "memory"); }
    __builtin_amdgcn_sched_barrier(0);
    // PV: yacc[k][jj] += d[ct][ch] * P[jt][ch]
    __builtin_amdgcn_s_setprio(1);
#pragma unroll
    for (int ch = 0; ch < 4; ++ch) {
#pragma unroll
      for (int jj = 0; jj < 2; ++jj) {
        int jt = 2 * jg + jj;
        const s16x8 pfv = *reinterpret_cast<const s16x8*>(pbuf + ((jt * 4 + ch) * 64 + l) * 8);
        yacc[0][jj] = MFMA32(dv[0][ch], pfv, yacc[0][jj]);
        yacc[1][jj] = MFMA32(dv[1][ch], pfv, yacc[1][jj]);
      }
    }
    __builtin_amdgcn_s_setprio(0);
  }

  // ---- epilogue: out = x + Y
#pragma unroll
  for (int k = 0; k < 2; ++k) {
#pragma unroll
    for (int jj = 0; jj < 2; ++jj) {
#pragma unroll
      for (int r = 0; r < 16; ++r) {
        int row = cb2 * 256 + cg * 64 + 32 * k + (r & 3) + 8 * (r >> 2) + 4 * hi;
        int col = jB * 128 + jg * 64 + 32 * jj + l31;
        size_t idx = ((size_t)b * 512 + row) * 4096 + col;
        out[idx] = x[idx] + yacc[k][jj][r];
      }
    }
  }
}

extern "C" void kernel_launch(void* const* d_in, const int* in_sizes, int n_in,
                              void* d_out, int out_size, void* d_ws, size_t ws_size,
                              hipStream_t stream) {
  const float* x  = (const float*)d_in[0];
  const float* Wb = (const float*)d_in[1];
  const float* bb = (const float*)d_in[2];
  const float* Wc = (const float*)d_in[3];
  const float* bc = (const float*)d_in[4];
  const float* Wd = (const float*)d_in[5];
  const float* bd = (const float*)d_in[6];
  char* ws = (char*)d_ws;
  ushort* xT   = (ushort*)(ws + WS_XT);
  ushort* dmat = (ushort*)(ws + WS_D);
  ushort* bT   = (ushort*)(ws + WS_BT);
  ushort* cT   = (ushort*)(ws + WS_CT);
  ushort* Wcat = (ushort*)(ws + WS_WCAT);
  float*  bcat = (float*)(ws + WS_BCAT);
  float*  out  = (float*)d_out;

  k_prep_w<<<1280, 256, 0, stream>>>(Wb, bb, Wc, bc, Wd, bd, Wcat, bcat);
  k_prep_xt<<<2048, 256, 0, stream>>>(x, xT);
  k_proj<<<640, 256, 0, stream>>>(Wcat, bcat, xT, bT, cT, dmat);
  k_stats<<<256, 512, 0, stream>>>(bT, cT, dmat);
  k_attn<<<256, 512, 0, stream>>>(bT, cT, dmat, x, out);
}